// Round 2
// baseline (4230.164 us; speedup 1.0000x reference)
//
#include <hip/hip_runtime.h>
#include <math.h>

#define PI_F 3.14159265358979323846f

__device__ __forceinline__ float gelu_f(float x) {
    return 0.5f * x * (1.0f + erff(x * 0.70710678118654752440f));
}

// ---------------- twiddle tables ----------------
// tabF: [w][ky*2+c]   (4096)  c0=cos(2pi ky w/128), c1=-sin
// tabH: [h][kxi*2+c]  (8192)  e^{-i 2pi f(kxi) h/128}, f=kxi<16?kxi:kxi-32
// tabI: [ky][w*2+c]   (4096)  (cos, -sin) of 2pi ky w/128
__global__ void k_init_tables(float* __restrict__ tabF, float* __restrict__ tabH,
                              float* __restrict__ tabI) {
    int idx = blockIdx.x * 256 + threadIdx.x;
    if (idx < 4096) {
        int w = idx >> 5, q = idx & 31, ky = q >> 1, c = q & 1;
        int m = (ky * w) & 127;
        float th = (2.0f * PI_F / 128.0f) * (float)m;
        tabF[idx] = c ? -sinf(th) : cosf(th);
    }
    if (idx < 8192) {
        int c = idx & 1, kxi = (idx >> 1) & 31, h = idx >> 6;
        int f = kxi < 16 ? kxi : kxi - 32;
        int m = ((f * h) % 128 + 128) & 127;
        float th = (2.0f * PI_F / 128.0f) * (float)m;
        tabH[idx] = c ? -sinf(th) : cosf(th);
    }
    if (idx < 4096) {
        int c = idx & 1, w = (idx >> 1) & 127, ky = idx >> 8;
        int m = (ky * w) & 127;
        float th = (2.0f * PI_F / 128.0f) * (float)m;
        tabI[idx] = c ? -sinf(th) : cosf(th);
    }
}

// ---------------- lifting: (B,H,W,2)+grid -> (B,C,H,W) ----------------
__global__ __launch_bounds__(256) void k_lift(const float* __restrict__ xin,
        const float* __restrict__ w0, const float* __restrict__ b0,
        float* __restrict__ xout) {
    int idx = blockIdx.x * 256 + threadIdx.x;
    int w = idx & 127, h = (idx >> 7) & 127, c = (idx >> 14) & 127, b = idx >> 21;
    const float* xp = xin + ((b * 128 + h) * 128 + w) * 2;
    float v = xp[0] * w0[c] + xp[1] * w0[128 + c]
            + ((float)h * (1.0f / 127.0f)) * w0[256 + c]
            + ((float)w * (1.0f / 127.0f)) * w0[384 + c] + b0[c];
    xout[idx] = v;
}

// ---------------- forward DFT along w: x(B,C,H,W) -> T(B,C,H,16)cplx ----------------
__global__ __launch_bounds__(256) void k_dft_w(const float* __restrict__ x,
        float* __restrict__ T, const float* __restrict__ tabF) {
    __shared__ float xs[1024];
    __shared__ float tw[4096];
    int t = threadIdx.x;
    int r0 = blockIdx.x * 8;               // 8 rows (b,c,h) per block
    #pragma unroll
    for (int k = 0; k < 16; ++k) tw[k * 256 + t] = tabF[k * 256 + t];
    const float* xp = x + (size_t)r0 * 128;
    #pragma unroll
    for (int k = 0; k < 4; ++k) xs[k * 256 + t] = xp[k * 256 + t];
    __syncthreads();
    int rl = t >> 5, q = t & 31;           // q = ky*2 + (re/im)
    const float* xr = xs + rl * 128;
    float acc = 0.0f;
    #pragma unroll
    for (int w = 0; w < 128; ++w) acc += xr[w] * tw[w * 32 + q];
    T[(size_t)r0 * 32 + t] = acc;
}

// ---------------- forward DFT along h: T -> F(B,C,32,16)cplx [b][i][m] ----------------
__global__ __launch_bounds__(256) void k_dft_h(const float* __restrict__ T,
        float* __restrict__ F, const float* __restrict__ tabH) {
    __shared__ float Ts[4096];
    __shared__ float Eh[8192];
    int t = threadIdx.x, bi = blockIdx.x;  // bi = b*128 + i
    #pragma unroll
    for (int k = 0; k < 32; ++k) Eh[k * 256 + t] = tabH[k * 256 + t];
    const float* Tp = T + (size_t)bi * 4096;
    #pragma unroll
    for (int k = 0; k < 16; ++k) Ts[k * 256 + t] = Tp[k * 256 + t];
    __syncthreads();
    int kxi = t & 31, g = t >> 5;
    int ky0 = g * 2;
    float ar0 = 0.f, ai0 = 0.f, ar1 = 0.f, ai1 = 0.f;
    for (int h = 0; h < 128; ++h) {
        float er = Eh[h * 64 + kxi * 2], ei = Eh[h * 64 + kxi * 2 + 1];
        float tr0 = Ts[h * 32 + ky0 * 2],     ti0 = Ts[h * 32 + ky0 * 2 + 1];
        float tr1 = Ts[h * 32 + ky0 * 2 + 2], ti1 = Ts[h * 32 + ky0 * 2 + 3];
        ar0 += tr0 * er - ti0 * ei;  ai0 += tr0 * ei + ti0 * er;
        ar1 += tr1 * er - ti1 * ei;  ai1 += tr1 * ei + ti1 * er;
    }
    *(float4*)(F + (size_t)bi * 1024 + (kxi * 16 + ky0) * 2) = make_float4(ar0, ai0, ar1, ai1);
}

// ---------------- per-mode complex C x C mix: F -> G [b][o][m] ----------------
__global__ __launch_bounds__(256) void k_modemix(const float* __restrict__ F,
        float* __restrict__ G,
        const float* __restrict__ w1r, const float* __restrict__ w1i,
        const float* __restrict__ w2r, const float* __restrict__ w2i) {
    int t = threadIdx.x;
    int m = blockIdx.x * 64 + (t & 63);
    int o = blockIdx.y * 4 + (t >> 6);
    const float* wrp = (m < 256) ? w1r : w2r;
    const float* wip = (m < 256) ? w1i : w2i;
    int ms = m & 255;
    float accr[16], acci[16];
    #pragma unroll
    for (int b = 0; b < 16; ++b) { accr[b] = 0.f; acci[b] = 0.f; }
    for (int i = 0; i < 128; ++i) {
        float wr = wrp[(i * 128 + o) * 256 + ms];
        float wi = wip[(i * 128 + o) * 256 + ms];
        const float* Fp = F + i * 1024 + m * 2;
        #pragma unroll
        for (int b = 0; b < 16; ++b) {
            float fr = Fp[b * 131072];
            float fi = Fp[b * 131072 + 1];
            accr[b] += fr * wr - fi * wi;
            acci[b] += fr * wi + fi * wr;
        }
    }
    #pragma unroll
    for (int b = 0; b < 16; ++b) {
        float* Gp = G + ((size_t)(b * 128 + o) * 512 + m) * 2;
        Gp[0] = accr[b]; Gp[1] = acci[b];
    }
}

// ---------------- inverse DFT along h: G -> Z(B,C,H,16)cplx ----------------
__global__ __launch_bounds__(256) void k_idft_h(const float* __restrict__ G,
        float* __restrict__ Z, const float* __restrict__ tabH) {
    __shared__ float Gs[1024];
    __shared__ float Eh[8192];
    int t = threadIdx.x, bo = blockIdx.x;
    #pragma unroll
    for (int k = 0; k < 32; ++k) Eh[k * 256 + t] = tabH[k * 256 + t];
    const float* Gp = G + (size_t)bo * 1024;
    #pragma unroll
    for (int k = 0; k < 4; ++k) Gs[k * 256 + t] = Gp[k * 256 + t];
    __syncthreads();
    int ky = t & 15, hb = t >> 4;
    float zr[8], zi[8];
    #pragma unroll
    for (int j = 0; j < 8; ++j) { zr[j] = 0.f; zi[j] = 0.f; }
    for (int kxi = 0; kxi < 32; ++kxi) {
        float gr = Gs[(kxi * 16 + ky) * 2], gi = Gs[(kxi * 16 + ky) * 2 + 1];
        #pragma unroll
        for (int j = 0; j < 8; ++j) {
            int h = hb + 16 * j;
            float c = Eh[h * 64 + kxi * 2], s = Eh[h * 64 + kxi * 2 + 1];
            zr[j] += gr * c + gi * s;   // Re(G * e^{+i phi}), s = -sin(phi)
            zi[j] += gi * c - gr * s;
        }
    }
    float* Zp = Z + (size_t)bo * 4096;
    #pragma unroll
    for (int j = 0; j < 8; ++j) {
        int h = hb + 16 * j;
        Zp[h * 32 + ky * 2] = zr[j];
        Zp[h * 32 + ky * 2 + 1] = zi[j];
    }
}

// ---------------- fused layer tail: Z -> S (inline idft_w) -> MLP + skip ----------------
// out = [gelu]( W2 . gelu(W1 . S + b1) + b2 + Wsk . x + bsk ), written in-place over x.
template<int ACT>
__global__ __launch_bounds__(256) void k_layer(
    const float* __restrict__ Zbuf, const float* __restrict__ xin,
    const float* __restrict__ w1, const float* __restrict__ b1,
    const float* __restrict__ w2, const float* __restrict__ b2,
    const float* __restrict__ wsk, const float* __restrict__ bsk,
    const float* __restrict__ tabI, float* __restrict__ xout)
{
    __shared__ float Ss[8192];   // S tile [128ch][64px], later reused as Mid
    __shared__ float Wc[4224];   // weight chunk [128o][33]
    __shared__ float Aux[2048];  // Z half-staging / x chunk staging
    int t = threadIdx.x;
    int b = blockIdx.y;
    int p0 = blockIdx.x * 64;
    int h = p0 >> 7, w0 = p0 & 127;

    // ---- P0: build S tile via 16-mode inverse w-DFT ----
    {
        int wl = t & 63, cq = t >> 6;
        int w = w0 + wl;
        float cr[16], ci[16];
        #pragma unroll
        for (int ky = 0; ky < 16; ++ky) {
            cr[ky] = tabI[ky * 256 + w * 2];
            ci[ky] = tabI[ky * 256 + w * 2 + 1];
        }
        for (int half = 0; half < 2; ++half) {
            int c0 = half * 64;
            __syncthreads();
            #pragma unroll
            for (int k = 0; k < 8; ++k) {
                int idx = k * 256 + t;
                int ky = (idx & 31) >> 1;
                float g = (ky == 0 ? 1.0f : 2.0f) * (1.0f / 16384.0f);
                Aux[idx] = Zbuf[((size_t)(b * 128 + c0 + (idx >> 5)) * 128 + h) * 32 + (idx & 31)] * g;
            }
            __syncthreads();
            #pragma unroll
            for (int j = 0; j < 16; ++j) {
                int cl = cq * 16 + j;
                const float4* zp = (const float4*)(Aux + cl * 32);
                float a = 0.f;
                #pragma unroll
                for (int kk = 0; kk < 8; ++kk) {
                    float4 z = zp[kk];   // Zr[2kk],Zi[2kk],Zr[2kk+1],Zi[2kk+1]
                    a += z.x * cr[2 * kk] + z.y * ci[2 * kk]
                       + z.z * cr[2 * kk + 1] + z.w * ci[2 * kk + 1];
                }
                Ss[(c0 + cl) * 64 + wl] = a;
            }
        }
    }

    int og = t >> 4, pg = t & 15;
    float acc[8][4];
    #pragma unroll
    for (int j = 0; j < 8; ++j)
        #pragma unroll
        for (int q = 0; q < 4; ++q) acc[j][q] = 0.f;

    // ---- P1: acc = W1 . S ----
    for (int ic = 0; ic < 4; ++ic) {
        __syncthreads();
        #pragma unroll
        for (int k = 0; k < 16; ++k) {
            int idx = k * 256 + t;
            Wc[(idx >> 5) * 33 + (idx & 31)] = w1[(idx >> 5) * 128 + ic * 32 + (idx & 31)];
        }
        __syncthreads();
        #pragma unroll 4
        for (int ii = 0; ii < 32; ++ii) {
            int i = ic * 32 + ii;
            float4 iv = *(const float4*)(Ss + i * 64 + pg * 4);
            float wv[8];
            #pragma unroll
            for (int j = 0; j < 8; ++j) wv[j] = Wc[(og * 8 + j) * 33 + ii];
            #pragma unroll
            for (int j = 0; j < 8; ++j) {
                acc[j][0] += wv[j] * iv.x; acc[j][1] += wv[j] * iv.y;
                acc[j][2] += wv[j] * iv.z; acc[j][3] += wv[j] * iv.w;
            }
        }
    }
    __syncthreads();                        // all S reads done
    // Mid = gelu(acc + b1) -> overwrite Ss
    #pragma unroll
    for (int j = 0; j < 8; ++j) {
        int o = og * 8 + j;
        float bb = b1[o];
        #pragma unroll
        for (int q = 0; q < 4; ++q)
            Ss[o * 64 + pg * 4 + q] = gelu_f(acc[j][q] + bb);
        #pragma unroll
        for (int q = 0; q < 4; ++q) acc[j][q] = 0.f;
    }

    // ---- P2: acc = W2 . Mid ----
    for (int ic = 0; ic < 4; ++ic) {
        __syncthreads();
        #pragma unroll
        for (int k = 0; k < 16; ++k) {
            int idx = k * 256 + t;
            Wc[(idx >> 5) * 33 + (idx & 31)] = w2[(idx >> 5) * 128 + ic * 32 + (idx & 31)];
        }
        __syncthreads();
        #pragma unroll 4
        for (int ii = 0; ii < 32; ++ii) {
            int i = ic * 32 + ii;
            float4 iv = *(const float4*)(Ss + i * 64 + pg * 4);
            float wv[8];
            #pragma unroll
            for (int j = 0; j < 8; ++j) wv[j] = Wc[(og * 8 + j) * 33 + ii];
            #pragma unroll
            for (int j = 0; j < 8; ++j) {
                acc[j][0] += wv[j] * iv.x; acc[j][1] += wv[j] * iv.y;
                acc[j][2] += wv[j] * iv.z; acc[j][3] += wv[j] * iv.w;
            }
        }
    }

    // ---- P3: acc += Wsk . x (stream x chunks through Aux) ----
    for (int ic = 0; ic < 4; ++ic) {
        __syncthreads();
        #pragma unroll
        for (int k = 0; k < 16; ++k) {
            int idx = k * 256 + t;
            Wc[(idx >> 5) * 33 + (idx & 31)] = wsk[(idx >> 5) * 128 + ic * 32 + (idx & 31)];
        }
        #pragma unroll
        for (int k = 0; k < 8; ++k) {
            int idx = k * 256 + t;
            Aux[idx] = xin[((size_t)b * 128 + ic * 32 + (idx >> 6)) * 16384 + p0 + (idx & 63)];
        }
        __syncthreads();
        #pragma unroll 4
        for (int ii = 0; ii < 32; ++ii) {
            float4 iv = *(const float4*)(Aux + ii * 64 + pg * 4);
            float wv[8];
            #pragma unroll
            for (int j = 0; j < 8; ++j) wv[j] = Wc[(og * 8 + j) * 33 + ii];
            #pragma unroll
            for (int j = 0; j < 8; ++j) {
                acc[j][0] += wv[j] * iv.x; acc[j][1] += wv[j] * iv.y;
                acc[j][2] += wv[j] * iv.z; acc[j][3] += wv[j] * iv.w;
            }
        }
    }

    // ---- epilogue: in-place write (all x reads for this block's pixels are done) ----
    #pragma unroll
    for (int j = 0; j < 8; ++j) {
        int o = og * 8 + j;
        float bb = b2[o] + bsk[o];
        float4 v;
        float* vp = (float*)&v;
        #pragma unroll
        for (int q = 0; q < 4; ++q) {
            float xv = acc[j][q] + bb;
            if (ACT) xv = gelu_f(xv);
            vp[q] = xv;
        }
        *(float4*)(xout + ((size_t)b * 128 + o) * 16384 + p0 + pg * 4) = v;
    }
}

// ---------------- fused projection: gelu(fc1a . x + ba) then fc1b dot ----------------
__global__ __launch_bounds__(256) void k_proj(const float* __restrict__ xin,
        const float* __restrict__ wa, const float* __restrict__ ba,
        const float* __restrict__ wb, const float* __restrict__ bb,
        float* __restrict__ outp) {
    __shared__ float Ss[8192];
    __shared__ float Wc[4224];
    __shared__ float Aux[2048];
    int t = threadIdx.x;
    int b = blockIdx.y;
    int p0 = blockIdx.x * 64;
    int og = t >> 4, pg = t & 15;
    float acc[8][4];
    #pragma unroll
    for (int j = 0; j < 8; ++j)
        #pragma unroll
        for (int q = 0; q < 4; ++q) acc[j][q] = 0.f;
    for (int ic = 0; ic < 4; ++ic) {
        __syncthreads();
        #pragma unroll
        for (int k = 0; k < 16; ++k) {
            int idx = k * 256 + t;
            Wc[(idx >> 5) * 33 + (idx & 31)] = wa[(idx >> 5) * 128 + ic * 32 + (idx & 31)];
        }
        #pragma unroll
        for (int k = 0; k < 8; ++k) {
            int idx = k * 256 + t;
            Aux[idx] = xin[((size_t)b * 128 + ic * 32 + (idx >> 6)) * 16384 + p0 + (idx & 63)];
        }
        __syncthreads();
        #pragma unroll 4
        for (int ii = 0; ii < 32; ++ii) {
            float4 iv = *(const float4*)(Aux + ii * 64 + pg * 4);
            float wv[8];
            #pragma unroll
            for (int j = 0; j < 8; ++j) wv[j] = Wc[(og * 8 + j) * 33 + ii];
            #pragma unroll
            for (int j = 0; j < 8; ++j) {
                acc[j][0] += wv[j] * iv.x; acc[j][1] += wv[j] * iv.y;
                acc[j][2] += wv[j] * iv.z; acc[j][3] += wv[j] * iv.w;
            }
        }
    }
    __syncthreads();
    #pragma unroll
    for (int j = 0; j < 8; ++j) {
        int o = og * 8 + j;
        float bba = ba[o];
        #pragma unroll
        for (int q = 0; q < 4; ++q)
            Ss[o * 64 + pg * 4 + q] = gelu_f(acc[j][q] + bba);
    }
    __syncthreads();
    int p = t & 63, iq = t >> 6;
    float s = 0.f;
    #pragma unroll
    for (int k = 0; k < 32; ++k) {
        int i = iq * 32 + k;
        s += wb[i] * Ss[i * 64 + p];
    }
    Aux[iq * 64 + p] = s;
    __syncthreads();
    if (t < 64)
        outp[(size_t)b * 16384 + p0 + t] = bb[0] + Aux[t] + Aux[64 + t] + Aux[128 + t] + Aux[192 + t];
}

extern "C" void kernel_launch(void* const* d_in, const int* in_sizes, int n_in,
                              void* d_out, int out_size, void* d_ws, size_t ws_size,
                              hipStream_t stream) {
    (void)in_sizes; (void)n_in; (void)out_size; (void)ws_size;
    const float* x     = (const float*)d_in[0];
    const float* w1r   = (const float*)d_in[1];
    const float* w1i   = (const float*)d_in[2];
    const float* w2r   = (const float*)d_in[3];
    const float* w2i   = (const float*)d_in[4];
    const float* mlp1w = (const float*)d_in[5];
    const float* mlp1b = (const float*)d_in[6];
    const float* mlp2w = (const float*)d_in[7];
    const float* mlp2b = (const float*)d_in[8];
    const float* wsw   = (const float*)d_in[9];
    const float* wsb   = (const float*)d_in[10];
    const float* fc0w  = (const float*)d_in[11];
    const float* fc0b  = (const float*)d_in[12];
    const float* fc1aw = (const float*)d_in[13];
    const float* fc1ab = (const float*)d_in[14];
    const float* fc1bw = (const float*)d_in[15];
    const float* fc1bb = (const float*)d_in[16];
    float* out = (float*)d_out;

    // workspace: 46,153,728 floats = 176.1 MiB total
    float* ws   = (float*)d_ws;
    float* xA   = ws;                        // 33,554,432 (B*C*H*W)
    float* T    = ws + 33554432;             //  8,388,608 (B*C*H*16 cplx)
    float* F    = T + 8388608;               //  2,097,152 (B*C*512 cplx)
    float* G    = F + 2097152;               //  2,097,152
    float* tabF = G + 2097152;               //  4096
    float* tabH = tabF + 4096;               //  8192
    float* tabI = tabH + 8192;               //  4096

    k_init_tables<<<32, 256, 0, stream>>>(tabF, tabH, tabI);
    k_lift<<<131072, 256, 0, stream>>>(x, fc0w, fc0b, xA);

    for (int l = 0; l < 4; ++l) {
        k_dft_w<<<32768, 256, 0, stream>>>(xA, T, tabF);
        k_dft_h<<<2048, 256, 0, stream>>>(T, F, tabH);
        k_modemix<<<dim3(8, 32), 256, 0, stream>>>(F, G,
            w1r + (size_t)l * 4194304, w1i + (size_t)l * 4194304,
            w2r + (size_t)l * 4194304, w2i + (size_t)l * 4194304);
        k_idft_h<<<2048, 256, 0, stream>>>(G, T, tabH);
        if (l < 3)
            k_layer<1><<<dim3(256, 16), 256, 0, stream>>>(T, xA,
                mlp1w + l * 16384, mlp1b + l * 128,
                mlp2w + l * 16384, mlp2b + l * 128,
                wsw + l * 16384, wsb + l * 128, tabI, xA);
        else
            k_layer<0><<<dim3(256, 16), 256, 0, stream>>>(T, xA,
                mlp1w + l * 16384, mlp1b + l * 128,
                mlp2w + l * 16384, mlp2b + l * 128,
                wsw + l * 16384, wsb + l * 128, tabI, xA);
    }
    k_proj<<<dim3(256, 16), 256, 0, stream>>>(xA, fc1aw, fc1ab, fc1bw, fc1bb, out);
}

// Round 3
// 2820.303 us; speedup vs baseline: 1.4999x; 1.4999x over previous
//
#include <hip/hip_runtime.h>
#include <math.h>

#define PI_F 3.14159265358979323846f

typedef __attribute__((ext_vector_type(8))) short s8v;
typedef __attribute__((ext_vector_type(4))) short s4v;
typedef __attribute__((ext_vector_type(4))) float f4v;

#define MFMA16(a, b, c) __builtin_amdgcn_mfma_f32_16x16x32_bf16(a, b, c, 0, 0, 0)

__device__ __forceinline__ float gelu_f(float x) {
    return 0.5f * x * (1.0f + erff(x * 0.70710678118654752440f));
}

__device__ __forceinline__ unsigned bf16_rn_bits(float x) {
    unsigned u = __builtin_bit_cast(unsigned, x);
    return (u + 0x7FFFu + ((u >> 16) & 1u)) & 0xFFFF0000u;
}
__device__ __forceinline__ void split_bf16(float x, unsigned short& h, unsigned short& l) {
    unsigned hb = bf16_rn_bits(x);
    float hf = __builtin_bit_cast(float, hb);
    h = (unsigned short)(hb >> 16);
    l = (unsigned short)(bf16_rn_bits(x - hf) >> 16);
}

// pack 8 fp32 (consecutive k, k0 multiple of 8) into swizzled hi/lo LDS B-buffer
// B-buffer logical layout: [px 0..63][k 0..127] bf16, hi plane @0, lo plane @16384
// swizzle: byte ^= ((px&7)<<4)  (st_16x32)
__device__ __forceinline__ void pack_write8(char* Bb, int px, int k0, const float* v) {
    s8v hv, lv;
    #pragma unroll
    for (int j = 0; j < 8; ++j) {
        unsigned short h, l;
        split_bf16(v[j], h, l);
        hv[j] = (short)h; lv[j] = (short)l;
    }
    int byt = px * 256 + ((k0 * 2) ^ ((px & 7) << 4));
    *(s8v*)(Bb + byt) = hv;
    *(s8v*)(Bb + 16384 + byt) = lv;
}

// one 128(o) x 64(px) x 128(k) GEMM accumulate via split-bf16 MFMA.
// wp: packed weights [prec][ot 8][kc 4][lane 64][j 8] ushort, plane stride 16384.
__device__ __forceinline__ void gemm_step(const char* Bb, const unsigned short* wp,
                                          int lane, int wv, f4v acc[2][4]) {
    #pragma unroll
    for (int kc = 0; kc < 4; ++kc) {
        s8v bh[4], bl[4];
        int k0 = kc * 32 + ((lane >> 4) << 3);
        #pragma unroll
        for (int pt = 0; pt < 4; ++pt) {
            int px = pt * 16 + (lane & 15);
            int byt = px * 256 + ((k0 * 2) ^ ((px & 7) << 4));
            bh[pt] = *(const s8v*)(Bb + byt);
            bl[pt] = *(const s8v*)(Bb + 16384 + byt);
        }
        #pragma unroll
        for (int oi = 0; oi < 2; ++oi) {
            const unsigned short* ap = wp + (wv * 2 + oi) * 2048 + kc * 512 + lane * 8;
            s8v ah = *(const s8v*)ap;
            s8v al = *(const s8v*)(ap + 16384);
            #pragma unroll
            for (int pt = 0; pt < 4; ++pt) {
                acc[oi][pt] = MFMA16(ah, bh[pt], acc[oi][pt]);
                acc[oi][pt] = MFMA16(ah, bl[pt], acc[oi][pt]);
                acc[oi][pt] = MFMA16(al, bh[pt], acc[oi][pt]);
            }
        }
    }
}

// ---------------- weight pre-split+pack: 13 fp32 128x128 mats -> hi/lo bf16 frag order ----
__global__ __launch_bounds__(256) void k_pack_w(const float* __restrict__ mlp1w,
        const float* __restrict__ mlp2w, const float* __restrict__ wsw,
        const float* __restrict__ fc1aw, unsigned short* __restrict__ wpack) {
    int idx = blockIdx.x * 256 + threadIdx.x;
    if (idx >= 212992) return;           // 13 * 16384
    int mat = idx >> 14, e = idx & 16383;
    const float* src = mat < 4  ? mlp1w + mat * 16384 + e
                     : mat < 8  ? mlp2w + (mat - 4) * 16384 + e
                     : mat < 12 ? wsw + (mat - 8) * 16384 + e
                                : fc1aw + e;
    float x = *src;
    unsigned short h, l;
    split_bf16(x, h, l);
    int o = e >> 7, i = e & 127;
    int pos = (o >> 4) * 2048 + (i >> 5) * 512 + (((i >> 3) & 3) * 16 + (o & 15)) * 8 + (i & 7);
    wpack[(size_t)mat * 32768 + pos] = h;
    wpack[(size_t)mat * 32768 + 16384 + pos] = l;
}

// ---------------- twiddle tables ----------------
__global__ void k_init_tables(float* __restrict__ tabF, float* __restrict__ tabH,
                              float* __restrict__ tabI) {
    int idx = blockIdx.x * 256 + threadIdx.x;
    if (idx < 4096) {
        int w = idx >> 5, q = idx & 31, ky = q >> 1, c = q & 1;
        int m = (ky * w) & 127;
        float th = (2.0f * PI_F / 128.0f) * (float)m;
        tabF[idx] = c ? -sinf(th) : cosf(th);
    }
    if (idx < 8192) {
        int c = idx & 1, kxi = (idx >> 1) & 31, h = idx >> 6;
        int f = kxi < 16 ? kxi : kxi - 32;
        int m = ((f * h) % 128 + 128) & 127;
        float th = (2.0f * PI_F / 128.0f) * (float)m;
        tabH[idx] = c ? -sinf(th) : cosf(th);
    }
    if (idx < 4096) {
        int c = idx & 1, w = (idx >> 1) & 127, ky = idx >> 8;
        int m = (ky * w) & 127;
        float th = (2.0f * PI_F / 128.0f) * (float)m;
        tabI[idx] = c ? -sinf(th) : cosf(th);
    }
}

// ---------------- lifting ----------------
__global__ __launch_bounds__(256) void k_lift(const float* __restrict__ xin,
        const float* __restrict__ w0, const float* __restrict__ b0,
        float* __restrict__ xout) {
    int idx = blockIdx.x * 256 + threadIdx.x;
    int w = idx & 127, h = (idx >> 7) & 127, c = (idx >> 14) & 127, b = idx >> 21;
    const float* xp = xin + ((b * 128 + h) * 128 + w) * 2;
    float v = xp[0] * w0[c] + xp[1] * w0[128 + c]
            + ((float)h * (1.0f / 127.0f)) * w0[256 + c]
            + ((float)w * (1.0f / 127.0f)) * w0[384 + c] + b0[c];
    xout[idx] = v;
}

// ---------------- forward DFT along w ----------------
__global__ __launch_bounds__(256) void k_dft_w(const float* __restrict__ x,
        float* __restrict__ T, const float* __restrict__ tabF) {
    __shared__ float xs[1024];
    __shared__ float tw[4096];
    int t = threadIdx.x;
    int r0 = blockIdx.x * 8;
    #pragma unroll
    for (int k = 0; k < 16; ++k) tw[k * 256 + t] = tabF[k * 256 + t];
    const float* xp = x + (size_t)r0 * 128;
    #pragma unroll
    for (int k = 0; k < 4; ++k) xs[k * 256 + t] = xp[k * 256 + t];
    __syncthreads();
    int rl = t >> 5, q = t & 31;
    const float* xr = xs + rl * 128;
    float acc = 0.0f;
    #pragma unroll
    for (int w = 0; w < 128; ++w) acc += xr[w] * tw[w * 32 + q];
    T[(size_t)r0 * 32 + t] = acc;
}

// ---------------- forward DFT along h ----------------
__global__ __launch_bounds__(256) void k_dft_h(const float* __restrict__ T,
        float* __restrict__ F, const float* __restrict__ tabH) {
    __shared__ float Ts[4096];
    __shared__ float Eh[8192];
    int t = threadIdx.x, bi = blockIdx.x;
    #pragma unroll
    for (int k = 0; k < 32; ++k) Eh[k * 256 + t] = tabH[k * 256 + t];
    const float* Tp = T + (size_t)bi * 4096;
    #pragma unroll
    for (int k = 0; k < 16; ++k) Ts[k * 256 + t] = Tp[k * 256 + t];
    __syncthreads();
    int kxi = t & 31, g = t >> 5;
    int ky0 = g * 2;
    float ar0 = 0.f, ai0 = 0.f, ar1 = 0.f, ai1 = 0.f;
    for (int h = 0; h < 128; ++h) {
        float er = Eh[h * 64 + kxi * 2], ei = Eh[h * 64 + kxi * 2 + 1];
        float tr0 = Ts[h * 32 + ky0 * 2],     ti0 = Ts[h * 32 + ky0 * 2 + 1];
        float tr1 = Ts[h * 32 + ky0 * 2 + 2], ti1 = Ts[h * 32 + ky0 * 2 + 3];
        ar0 += tr0 * er - ti0 * ei;  ai0 += tr0 * ei + ti0 * er;
        ar1 += tr1 * er - ti1 * ei;  ai1 += tr1 * ei + ti1 * er;
    }
    *(float4*)(F + (size_t)bi * 1024 + (kxi * 16 + ky0) * 2) = make_float4(ar0, ai0, ar1, ai1);
}

// ---------------- per-mode complex C x C mix ----------------
__global__ __launch_bounds__(256) void k_modemix(const float* __restrict__ F,
        float* __restrict__ G,
        const float* __restrict__ w1r, const float* __restrict__ w1i,
        const float* __restrict__ w2r, const float* __restrict__ w2i) {
    int t = threadIdx.x;
    int m = blockIdx.x * 64 + (t & 63);
    int o = blockIdx.y * 4 + (t >> 6);
    const float* wrp = (m < 256) ? w1r : w2r;
    const float* wip = (m < 256) ? w1i : w2i;
    int ms = m & 255;
    float accr[16], acci[16];
    #pragma unroll
    for (int b = 0; b < 16; ++b) { accr[b] = 0.f; acci[b] = 0.f; }
    for (int i = 0; i < 128; ++i) {
        float wr = wrp[(i * 128 + o) * 256 + ms];
        float wi = wip[(i * 128 + o) * 256 + ms];
        const float* Fp = F + i * 1024 + m * 2;
        #pragma unroll
        for (int b = 0; b < 16; ++b) {
            float fr = Fp[b * 131072];
            float fi = Fp[b * 131072 + 1];
            accr[b] += fr * wr - fi * wi;
            acci[b] += fr * wi + fi * wr;
        }
    }
    #pragma unroll
    for (int b = 0; b < 16; ++b) {
        float* Gp = G + ((size_t)(b * 128 + o) * 512 + m) * 2;
        Gp[0] = accr[b]; Gp[1] = acci[b];
    }
}

// ---------------- inverse DFT along h ----------------
__global__ __launch_bounds__(256) void k_idft_h(const float* __restrict__ G,
        float* __restrict__ Z, const float* __restrict__ tabH) {
    __shared__ float Gs[1024];
    __shared__ float Eh[8192];
    int t = threadIdx.x, bo = blockIdx.x;
    #pragma unroll
    for (int k = 0; k < 32; ++k) Eh[k * 256 + t] = tabH[k * 256 + t];
    const float* Gp = G + (size_t)bo * 1024;
    #pragma unroll
    for (int k = 0; k < 4; ++k) Gs[k * 256 + t] = Gp[k * 256 + t];
    __syncthreads();
    int ky = t & 15, hb = t >> 4;
    float zr[8], zi[8];
    #pragma unroll
    for (int j = 0; j < 8; ++j) { zr[j] = 0.f; zi[j] = 0.f; }
    for (int kxi = 0; kxi < 32; ++kxi) {
        float gr = Gs[(kxi * 16 + ky) * 2], gi = Gs[(kxi * 16 + ky) * 2 + 1];
        #pragma unroll
        for (int j = 0; j < 8; ++j) {
            int h = hb + 16 * j;
            float c = Eh[h * 64 + kxi * 2], s = Eh[h * 64 + kxi * 2 + 1];
            zr[j] += gr * c + gi * s;
            zi[j] += gi * c - gr * s;
        }
    }
    float* Zp = Z + (size_t)bo * 4096;
    #pragma unroll
    for (int j = 0; j < 8; ++j) {
        int h = hb + 16 * j;
        Zp[h * 32 + ky * 2] = zr[j];
        Zp[h * 32 + ky * 2 + 1] = zi[j];
    }
}

// ---------------- fused layer tail (MFMA split-bf16): Z -> S -> MLP + skip, in-place ----
template<int ACT>
__global__ __launch_bounds__(256) void k_layer(
    const float* __restrict__ Zbuf, const float* __restrict__ xin,
    const unsigned short* __restrict__ w1p, const float* __restrict__ b1,
    const unsigned short* __restrict__ w2p, const float* __restrict__ b2,
    const unsigned short* __restrict__ wskp, const float* __restrict__ bsk,
    const float* __restrict__ tabI, float* __restrict__ xout)
{
    __shared__ __align__(16) char Bb[32768];   // hi plane 16K + lo plane 16K
    __shared__ __align__(16) float Aux[2048];
    int t = threadIdx.x;
    int b = blockIdx.y;
    int p0 = blockIdx.x * 64;
    int h = p0 >> 7, w0 = p0 & 127;
    int lane = t & 63, wv = t >> 6;

    // ---- P0: S tile via 16-mode inverse w-DFT, pack into Bb ----
    {
        int wl = lane, cq = wv;
        int w = w0 + wl;
        float cr[16], ci[16];
        #pragma unroll
        for (int ky = 0; ky < 16; ++ky) {
            cr[ky] = tabI[ky * 256 + w * 2];
            ci[ky] = tabI[ky * 256 + w * 2 + 1];
        }
        for (int half = 0; half < 2; ++half) {
            int c0 = half * 64;
            __syncthreads();
            #pragma unroll
            for (int k = 0; k < 8; ++k) {
                int idx = k * 256 + t;
                int ky = (idx & 31) >> 1;
                float g = (ky == 0 ? 1.0f : 2.0f) * (1.0f / 16384.0f);
                Aux[idx] = Zbuf[((size_t)(b * 128 + c0 + (idx >> 5)) * 128 + h) * 32 + (idx & 31)] * g;
            }
            __syncthreads();
            float sv[16];
            #pragma unroll
            for (int j = 0; j < 16; ++j) {
                int cl = cq * 16 + j;
                const float4* zp = (const float4*)(Aux + cl * 32);
                float a = 0.f;
                #pragma unroll
                for (int kk = 0; kk < 8; ++kk) {
                    float4 z = zp[kk];
                    a += z.x * cr[2 * kk] + z.y * ci[2 * kk]
                       + z.z * cr[2 * kk + 1] + z.w * ci[2 * kk + 1];
                }
                sv[j] = a;
            }
            int k0 = c0 + cq * 16;
            pack_write8(Bb, wl, k0, sv);
            pack_write8(Bb, wl, k0 + 8, sv + 8);
        }
    }
    __syncthreads();

    f4v acc[2][4];
    #pragma unroll
    for (int oi = 0; oi < 2; ++oi)
        #pragma unroll
        for (int pt = 0; pt < 4; ++pt) acc[oi][pt] = (f4v){0.f, 0.f, 0.f, 0.f};

    // ---- P1: acc = W1 . S ----
    gemm_step(Bb, w1p, lane, wv, acc);
    __syncthreads();                       // all S reads done
    // Mid = gelu(acc + b1) -> overwrite Bb
    #pragma unroll
    for (int oi = 0; oi < 2; ++oi) {
        int o0 = wv * 32 + oi * 16 + ((lane >> 4) << 2);
        float bv[4];
        #pragma unroll
        for (int r = 0; r < 4; ++r) bv[r] = b1[o0 + r];
        #pragma unroll
        for (int pt = 0; pt < 4; ++pt) {
            int px = pt * 16 + (lane & 15);
            s4v h4, l4;
            #pragma unroll
            for (int r = 0; r < 4; ++r) {
                unsigned short hh, ll;
                split_bf16(gelu_f(acc[oi][pt][r] + bv[r]), hh, ll);
                h4[r] = (short)hh; l4[r] = (short)ll;
            }
            int byt = px * 256 + ((o0 * 2) ^ ((px & 7) << 4));
            *(s4v*)(Bb + byt) = h4;
            *(s4v*)(Bb + 16384 + byt) = l4;
            acc[oi][pt] = (f4v){0.f, 0.f, 0.f, 0.f};
        }
    }
    __syncthreads();

    // ---- P2: acc = W2 . Mid ----
    gemm_step(Bb, w2p, lane, wv, acc);
    __syncthreads();                       // all Mid reads done

    // ---- P3: stage x into Bb (4 passes), then acc += Wsk . x ----
    for (int pp = 0; pp < 4; ++pp) {
        #pragma unroll
        for (int k = 0; k < 8; ++k) {
            int idx = k * 256 + t;
            Aux[idx] = xin[((size_t)(b * 128 + pp * 32 + (idx >> 6))) * 16384 + p0 + (idx & 63)];
        }
        __syncthreads();
        {
            int px = lane, cq = wv;
            float v[8];
            #pragma unroll
            for (int j = 0; j < 8; ++j) v[j] = Aux[(cq * 8 + j) * 64 + px];
            pack_write8(Bb, px, pp * 32 + cq * 8, v);
        }
        __syncthreads();
    }
    gemm_step(Bb, wskp, lane, wv, acc);

    // ---- epilogue: in-place write ----
    #pragma unroll
    for (int oi = 0; oi < 2; ++oi) {
        int o0 = wv * 32 + oi * 16 + ((lane >> 4) << 2);
        float bv[4];
        #pragma unroll
        for (int r = 0; r < 4; ++r) bv[r] = b2[o0 + r] + bsk[o0 + r];
        #pragma unroll
        for (int pt = 0; pt < 4; ++pt) {
            int px = pt * 16 + (lane & 15);
            #pragma unroll
            for (int r = 0; r < 4; ++r) {
                float xv = acc[oi][pt][r] + bv[r];
                if (ACT) xv = gelu_f(xv);
                xout[((size_t)(b * 128 + o0 + r)) * 16384 + p0 + px] = xv;
            }
        }
    }
}

// ---------------- fused projection (MFMA split-bf16 fc1a, then fc1b dot) ----------------
__global__ __launch_bounds__(256) void k_proj(const float* __restrict__ xin,
        const unsigned short* __restrict__ wap, const float* __restrict__ ba,
        const float* __restrict__ wb, const float* __restrict__ bb,
        float* __restrict__ outp) {
    __shared__ __align__(16) char Bb[32768];
    __shared__ __align__(16) float Aux[2048];
    int t = threadIdx.x;
    int b = blockIdx.y;
    int p0 = blockIdx.x * 64;
    int lane = t & 63, wv = t >> 6;

    for (int pp = 0; pp < 4; ++pp) {
        #pragma unroll
        for (int k = 0; k < 8; ++k) {
            int idx = k * 256 + t;
            Aux[idx] = xin[((size_t)(b * 128 + pp * 32 + (idx >> 6))) * 16384 + p0 + (idx & 63)];
        }
        __syncthreads();
        {
            float v[8];
            #pragma unroll
            for (int j = 0; j < 8; ++j) v[j] = Aux[(wv * 8 + j) * 64 + lane];
            pack_write8(Bb, lane, pp * 32 + wv * 8, v);
        }
        __syncthreads();
    }

    f4v acc[2][4];
    #pragma unroll
    for (int oi = 0; oi < 2; ++oi)
        #pragma unroll
        for (int pt = 0; pt < 4; ++pt) acc[oi][pt] = (f4v){0.f, 0.f, 0.f, 0.f};
    gemm_step(Bb, wap, lane, wv, acc);

    // mid = gelu(acc+ba); pxsum = sum_o wb[o]*mid
    float pxsum[4] = {0.f, 0.f, 0.f, 0.f};
    #pragma unroll
    for (int oi = 0; oi < 2; ++oi) {
        int o0 = wv * 32 + oi * 16 + ((lane >> 4) << 2);
        #pragma unroll
        for (int r = 0; r < 4; ++r) {
            float bav = ba[o0 + r];
            float wbv = wb[o0 + r];
            #pragma unroll
            for (int pt = 0; pt < 4; ++pt)
                pxsum[pt] += wbv * gelu_f(acc[oi][pt][r] + bav);
        }
    }
    __syncthreads();
    #pragma unroll
    for (int pt = 0; pt < 4; ++pt) {
        float v = pxsum[pt];
        v += __shfl_xor(v, 16);
        v += __shfl_xor(v, 32);
        if (lane < 16) Aux[wv * 64 + pt * 16 + lane] = v;
    }
    __syncthreads();
    if (t < 64)
        outp[(size_t)b * 16384 + p0 + t] = bb[0] + Aux[t] + Aux[64 + t] + Aux[128 + t] + Aux[192 + t];
}

extern "C" void kernel_launch(void* const* d_in, const int* in_sizes, int n_in,
                              void* d_out, int out_size, void* d_ws, size_t ws_size,
                              hipStream_t stream) {
    (void)in_sizes; (void)n_in; (void)out_size; (void)ws_size;
    const float* x     = (const float*)d_in[0];
    const float* w1r   = (const float*)d_in[1];
    const float* w1i   = (const float*)d_in[2];
    const float* w2r   = (const float*)d_in[3];
    const float* w2i   = (const float*)d_in[4];
    const float* mlp1w = (const float*)d_in[5];
    const float* mlp1b = (const float*)d_in[6];
    const float* mlp2w = (const float*)d_in[7];
    const float* mlp2b = (const float*)d_in[8];
    const float* wsw   = (const float*)d_in[9];
    const float* wsb   = (const float*)d_in[10];
    const float* fc0w  = (const float*)d_in[11];
    const float* fc0b  = (const float*)d_in[12];
    const float* fc1aw = (const float*)d_in[13];
    const float* fc1ab = (const float*)d_in[14];
    const float* fc1bw = (const float*)d_in[15];
    const float* fc1bb = (const float*)d_in[16];
    float* out = (float*)d_out;

    float* ws   = (float*)d_ws;
    float* xA   = ws;                        // 33,554,432
    float* T    = ws + 33554432;             //  8,388,608
    float* F    = T + 8388608;               //  2,097,152
    float* G    = F + 2097152;               //  2,097,152
    float* tabF = G + 2097152;               //  4096
    float* tabH = tabF + 4096;               //  8192
    float* tabI = tabH + 8192;               //  4096
    unsigned short* wpack = (unsigned short*)(tabI + 4096);  // 13*32768 ushort

    k_init_tables<<<32, 256, 0, stream>>>(tabF, tabH, tabI);
    k_pack_w<<<832, 256, 0, stream>>>(mlp1w, mlp2w, wsw, fc1aw, wpack);
    k_lift<<<131072, 256, 0, stream>>>(x, fc0w, fc0b, xA);

    for (int l = 0; l < 4; ++l) {
        k_dft_w<<<32768, 256, 0, stream>>>(xA, T, tabF);
        k_dft_h<<<2048, 256, 0, stream>>>(T, F, tabH);
        k_modemix<<<dim3(8, 32), 256, 0, stream>>>(F, G,
            w1r + (size_t)l * 4194304, w1i + (size_t)l * 4194304,
            w2r + (size_t)l * 4194304, w2i + (size_t)l * 4194304);
        k_idft_h<<<2048, 256, 0, stream>>>(G, T, tabH);
        const unsigned short* w1p  = wpack + (size_t)l * 32768;
        const unsigned short* w2p  = wpack + (size_t)(4 + l) * 32768;
        const unsigned short* wskp = wpack + (size_t)(8 + l) * 32768;
        if (l < 3)
            k_layer<1><<<dim3(256, 16), 256, 0, stream>>>(T, xA,
                w1p, mlp1b + l * 128, w2p, mlp2b + l * 128,
                wskp, wsb + l * 128, tabI, xA);
        else
            k_layer<0><<<dim3(256, 16), 256, 0, stream>>>(T, xA,
                w1p, mlp1b + l * 128, w2p, mlp2b + l * 128,
                wskp, wsb + l * 128, tabI, xA);
    }
    k_proj<<<dim3(256, 16), 256, 0, stream>>>(xA, wpack + (size_t)12 * 32768,
        fc1ab, fc1bw, fc1bb, out);
}

// Round 4
// 2082.192 us; speedup vs baseline: 2.0316x; 1.3545x over previous
//
#include <hip/hip_runtime.h>
#include <math.h>

#define PI_F 3.14159265358979323846f

typedef __attribute__((ext_vector_type(8))) short s8v;
typedef __attribute__((ext_vector_type(4))) short s4v;
typedef __attribute__((ext_vector_type(4))) float f4v;

#define MFMA16(a, b, c) __builtin_amdgcn_mfma_f32_16x16x32_bf16(a, b, c, 0, 0, 0)

// fast erf, A&S 7.1.26, |err| <= 1.5e-7
__device__ __forceinline__ float erf_f(float x) {
    float a = fabsf(x);
    float t = 1.0f / fmaf(0.3275911f, a, 1.0f);
    float p = t * fmaf(t, fmaf(t, fmaf(t, fmaf(t, 1.061405429f, -1.453152027f),
                1.421413741f), -0.284496736f), 0.254829592f);
    float r = 1.0f - p * __expf(-a * a);
    return copysignf(r, x);
}
__device__ __forceinline__ float gelu_f(float x) {
    return 0.5f * x * (1.0f + erf_f(x * 0.70710678118654752440f));
}

__device__ __forceinline__ unsigned bf16_rn_bits(float x) {
    unsigned u = __builtin_bit_cast(unsigned, x);
    return (u + 0x7FFFu + ((u >> 16) & 1u)) & 0xFFFF0000u;
}
__device__ __forceinline__ void split_bf16(float x, unsigned short& h, unsigned short& l) {
    unsigned hb = bf16_rn_bits(x);
    float hf = __builtin_bit_cast(float, hb);
    h = (unsigned short)(hb >> 16);
    l = (unsigned short)(bf16_rn_bits(x - hf) >> 16);
}

// pack 8 fp32 (consecutive k, k0 mult of 8) into swizzled hi/lo LDS B-buffer
// layout: [px 0..63][k 0..127] bf16, hi @0, lo @16384; byte ^= ((px&7)<<4)
__device__ __forceinline__ void pack_write8(char* Bb, int px, int k0, const float* v) {
    s8v hv, lv;
    #pragma unroll
    for (int j = 0; j < 8; ++j) {
        unsigned short h, l;
        split_bf16(v[j], h, l);
        hv[j] = (short)h; lv[j] = (short)l;
    }
    int byt = px * 256 + ((k0 * 2) ^ ((px & 7) << 4));
    *(s8v*)(Bb + byt) = hv;
    *(s8v*)(Bb + 16384 + byt) = lv;
}

// one 128(o) x 64(px) x 128(k) GEMM accumulate via split-bf16 MFMA.
__device__ __forceinline__ void gemm_step(const char* Bb, const unsigned short* wp,
                                          int lane, int wv, f4v acc[2][4]) {
    #pragma unroll
    for (int kc = 0; kc < 4; ++kc) {
        s8v bh[4], bl[4];
        int k0 = kc * 32 + ((lane >> 4) << 3);
        #pragma unroll
        for (int pt = 0; pt < 4; ++pt) {
            int px = pt * 16 + (lane & 15);
            int byt = px * 256 + ((k0 * 2) ^ ((px & 7) << 4));
            bh[pt] = *(const s8v*)(Bb + byt);
            bl[pt] = *(const s8v*)(Bb + 16384 + byt);
        }
        #pragma unroll
        for (int oi = 0; oi < 2; ++oi) {
            const unsigned short* ap = wp + (wv * 2 + oi) * 2048 + kc * 512 + lane * 8;
            s8v ah = *(const s8v*)ap;
            s8v al = *(const s8v*)(ap + 16384);
            #pragma unroll
            for (int pt = 0; pt < 4; ++pt) {
                acc[oi][pt] = MFMA16(ah, bh[pt], acc[oi][pt]);
                acc[oi][pt] = MFMA16(ah, bl[pt], acc[oi][pt]);
                acc[oi][pt] = MFMA16(al, bh[pt], acc[oi][pt]);
            }
        }
    }
}

// ---------------- weight pre-split+pack: 13 fp32 128x128 mats ----------------
__global__ __launch_bounds__(256) void k_pack_w(const float* __restrict__ mlp1w,
        const float* __restrict__ mlp2w, const float* __restrict__ wsw,
        const float* __restrict__ fc1aw, unsigned short* __restrict__ wpack) {
    int idx = blockIdx.x * 256 + threadIdx.x;
    if (idx >= 212992) return;           // 13 * 16384
    int mat = idx >> 14, e = idx & 16383;
    const float* src = mat < 4  ? mlp1w + mat * 16384 + e
                     : mat < 8  ? mlp2w + (mat - 4) * 16384 + e
                     : mat < 12 ? wsw + (mat - 8) * 16384 + e
                                : fc1aw + e;
    float x = *src;
    unsigned short h, l;
    split_bf16(x, h, l);
    int o = e >> 7, i = e & 127;
    int pos = (o >> 4) * 2048 + (i >> 5) * 512 + (((i >> 3) & 3) * 16 + (o & 15)) * 8 + (i & 7);
    wpack[(size_t)mat * 32768 + pos] = h;
    wpack[(size_t)mat * 32768 + 16384 + pos] = l;
}

// ---------------- forward-w DFT twiddle fragments (split-bf16 B-frags) ----------------
// efp[kc4][nt2][lane64][j8], hi @0, lo @4096 (ushort)
__global__ void k_pack_ef(unsigned short* __restrict__ efp) {
    int t = blockIdx.x * 256 + threadIdx.x;
    if (t >= 4096) return;
    int j = t & 7, lane = (t >> 3) & 63, nt = (t >> 9) & 1, kc = t >> 10;
    int w = kc * 32 + ((lane >> 4) << 3) + j;
    int q = nt * 16 + (lane & 15);
    int ky = q >> 1, c = q & 1;
    int m = (ky * w) & 127;
    float th = (2.0f * PI_F / 128.0f) * (float)m;
    float v = c ? -sinf(th) : cosf(th);
    unsigned short h, l;
    split_bf16(v, h, l);
    efp[t] = h;
    efp[4096 + t] = l;
}

// ---------------- twiddle tables (tabH for h-DFTs, tabI for inverse-w) --------
__global__ void k_init_tables(float* __restrict__ tabH, float* __restrict__ tabI) {
    int idx = blockIdx.x * 256 + threadIdx.x;
    if (idx < 8192) {
        int c = idx & 1, kxi = (idx >> 1) & 31, h = idx >> 6;
        int f = kxi < 16 ? kxi : kxi - 32;
        int m = ((f * h) % 128 + 128) & 127;
        float th = (2.0f * PI_F / 128.0f) * (float)m;
        tabH[idx] = c ? -sinf(th) : cosf(th);
    }
    if (idx < 4096) {
        int c = idx & 1, w = (idx >> 1) & 127, ky = idx >> 8;
        int m = (ky * w) & 127;
        float th = (2.0f * PI_F / 128.0f) * (float)m;
        tabI[idx] = c ? -sinf(th) : cosf(th);
    }
}

// ---------------- lifting ----------------
__global__ __launch_bounds__(256) void k_lift(const float* __restrict__ xin,
        const float* __restrict__ w0, const float* __restrict__ b0,
        float* __restrict__ xout) {
    int idx = blockIdx.x * 256 + threadIdx.x;
    int w = idx & 127, h = (idx >> 7) & 127, c = (idx >> 14) & 127, b = idx >> 21;
    const float* xp = xin + ((b * 128 + h) * 128 + w) * 2;
    float v = xp[0] * w0[c] + xp[1] * w0[128 + c]
            + ((float)h * (1.0f / 127.0f)) * w0[256 + c]
            + ((float)w * (1.0f / 127.0f)) * w0[384 + c] + b0[c];
    xout[idx] = v;
}

// ---------------- forward DFT along w via MFMA: x -> T(B,C,H,16)cplx ----------
__global__ __launch_bounds__(256) void k_dft_w2(const float* __restrict__ x,
        float* __restrict__ T, const unsigned short* __restrict__ efp) {
    __shared__ __align__(16) char Xb[32768];
    int t = threadIdx.x;
    size_t r0 = (size_t)blockIdx.x * 64;     // 64 rows (b,c,h)
    const float4* xg = (const float4*)(x + r0 * 128);
    #pragma unroll
    for (int k = 0; k < 8; ++k) {
        int idx4 = k * 256 + t;
        float4 f = xg[idx4];
        int row = idx4 >> 5;
        int w0 = (idx4 & 31) * 4;
        s4v h4, l4;
        const float* fp = (const float*)&f;
        #pragma unroll
        for (int q = 0; q < 4; ++q) {
            unsigned short hh, ll;
            split_bf16(fp[q], hh, ll);
            h4[q] = (short)hh; l4[q] = (short)ll;
        }
        int byt = row * 256 + ((w0 * 2) ^ ((row & 7) << 4));
        *(s4v*)(Xb + byt) = h4;
        *(s4v*)(Xb + 16384 + byt) = l4;
    }
    __syncthreads();
    int lane = t & 63, wv = t >> 6;
    f4v acc[2];
    acc[0] = (f4v){0.f, 0.f, 0.f, 0.f};
    acc[1] = (f4v){0.f, 0.f, 0.f, 0.f};
    #pragma unroll
    for (int kc = 0; kc < 4; ++kc) {
        int row = wv * 16 + (lane & 15);
        int k0 = kc * 32 + ((lane >> 4) << 3);
        int byt = row * 256 + ((k0 * 2) ^ ((row & 7) << 4));
        s8v ah = *(const s8v*)(Xb + byt);
        s8v al = *(const s8v*)(Xb + 16384 + byt);
        #pragma unroll
        for (int nt = 0; nt < 2; ++nt) {
            const unsigned short* bp = efp + ((kc * 2 + nt) * 64 + lane) * 8;
            s8v bh = *(const s8v*)bp;
            s8v bl = *(const s8v*)(bp + 4096);
            acc[nt] = MFMA16(ah, bh, acc[nt]);
            acc[nt] = MFMA16(ah, bl, acc[nt]);
            acc[nt] = MFMA16(al, bh, acc[nt]);
        }
    }
    #pragma unroll
    for (int nt = 0; nt < 2; ++nt)
        #pragma unroll
        for (int r = 0; r < 4; ++r)
            T[(r0 + wv * 16 + (lane >> 4) * 4 + r) * 32 + nt * 16 + (lane & 15)] = acc[nt][r];
}

// ---------------- forward DFT along h ----------------
__global__ __launch_bounds__(256) void k_dft_h(const float* __restrict__ T,
        float* __restrict__ F, const float* __restrict__ tabH) {
    __shared__ float Ts[4096];
    __shared__ float Eh[8192];
    int t = threadIdx.x, bi = blockIdx.x;
    #pragma unroll
    for (int k = 0; k < 32; ++k) Eh[k * 256 + t] = tabH[k * 256 + t];
    const float* Tp = T + (size_t)bi * 4096;
    #pragma unroll
    for (int k = 0; k < 16; ++k) Ts[k * 256 + t] = Tp[k * 256 + t];
    __syncthreads();
    int kxi = t & 31, g = t >> 5;
    int ky0 = g * 2;
    float ar0 = 0.f, ai0 = 0.f, ar1 = 0.f, ai1 = 0.f;
    for (int h = 0; h < 128; ++h) {
        float er = Eh[h * 64 + kxi * 2], ei = Eh[h * 64 + kxi * 2 + 1];
        float tr0 = Ts[h * 32 + ky0 * 2],     ti0 = Ts[h * 32 + ky0 * 2 + 1];
        float tr1 = Ts[h * 32 + ky0 * 2 + 2], ti1 = Ts[h * 32 + ky0 * 2 + 3];
        ar0 += tr0 * er - ti0 * ei;  ai0 += tr0 * ei + ti0 * er;
        ar1 += tr1 * er - ti1 * ei;  ai1 += tr1 * ei + ti1 * er;
    }
    *(float4*)(F + (size_t)bi * 1024 + (kxi * 16 + ky0) * 2) = make_float4(ar0, ai0, ar1, ai1);
}

// ---------------- per-mode complex C x C mix (b-split over z) ----------------
__global__ __launch_bounds__(256) void k_modemix(const float* __restrict__ F,
        float* __restrict__ G,
        const float* __restrict__ w1r, const float* __restrict__ w1i,
        const float* __restrict__ w2r, const float* __restrict__ w2i) {
    int t = threadIdx.x;
    int m = blockIdx.x * 64 + (t & 63);
    int o = blockIdx.y * 4 + (t >> 6);
    int b0 = blockIdx.z * 8;
    const float* wrp = (m < 256) ? w1r : w2r;
    const float* wip = (m < 256) ? w1i : w2i;
    int ms = m & 255;
    float accr[8], acci[8];
    #pragma unroll
    for (int b = 0; b < 8; ++b) { accr[b] = 0.f; acci[b] = 0.f; }
    #pragma unroll 2
    for (int i = 0; i < 128; ++i) {
        float wr = wrp[(i * 128 + o) * 256 + ms];
        float wi = wip[(i * 128 + o) * 256 + ms];
        const float* Fp = F + i * 1024 + m * 2 + (size_t)b0 * 131072;
        #pragma unroll
        for (int b = 0; b < 8; ++b) {
            float fr = Fp[b * 131072];
            float fi = Fp[b * 131072 + 1];
            accr[b] += fr * wr - fi * wi;
            acci[b] += fr * wi + fi * wr;
        }
    }
    #pragma unroll
    for (int b = 0; b < 8; ++b) {
        float* Gp = G + ((size_t)((b0 + b) * 128 + o) * 512 + m) * 2;
        Gp[0] = accr[b]; Gp[1] = acci[b];
    }
}

// ---------------- inverse DFT along h ----------------
__global__ __launch_bounds__(256) void k_idft_h(const float* __restrict__ G,
        float* __restrict__ Z, const float* __restrict__ tabH) {
    __shared__ float Gs[1024];
    __shared__ float Eh[8192];
    int t = threadIdx.x, bo = blockIdx.x;
    #pragma unroll
    for (int k = 0; k < 32; ++k) Eh[k * 256 + t] = tabH[k * 256 + t];
    const float* Gp = G + (size_t)bo * 1024;
    #pragma unroll
    for (int k = 0; k < 4; ++k) Gs[k * 256 + t] = Gp[k * 256 + t];
    __syncthreads();
    int ky = t & 15, hb = t >> 4;
    float zr[8], zi[8];
    #pragma unroll
    for (int j = 0; j < 8; ++j) { zr[j] = 0.f; zi[j] = 0.f; }
    for (int kxi = 0; kxi < 32; ++kxi) {
        float gr = Gs[(kxi * 16 + ky) * 2], gi = Gs[(kxi * 16 + ky) * 2 + 1];
        #pragma unroll
        for (int j = 0; j < 8; ++j) {
            int h = hb + 16 * j;
            float c = Eh[h * 64 + kxi * 2], s = Eh[h * 64 + kxi * 2 + 1];
            zr[j] += gr * c + gi * s;
            zi[j] += gi * c - gr * s;
        }
    }
    float* Zp = Z + (size_t)bo * 4096;
    #pragma unroll
    for (int j = 0; j < 8; ++j) {
        int h = hb + 16 * j;
        Zp[h * 32 + ky * 2] = zr[j];
        Zp[h * 32 + ky * 2 + 1] = zi[j];
    }
}

// ---------------- fused layer tail: Z -> S -> MLP + skip, in-place ----------------
template<int ACT>
__global__ __launch_bounds__(256, 3) void k_layer(
    const float* __restrict__ Zbuf, const float* __restrict__ xin,
    const unsigned short* __restrict__ w1p, const float* __restrict__ b1,
    const unsigned short* __restrict__ w2p, const float* __restrict__ b2,
    const unsigned short* __restrict__ wskp, const float* __restrict__ bsk,
    const float* __restrict__ tabI, float* __restrict__ xout)
{
    __shared__ __align__(16) char Bb[32768];
    __shared__ __align__(16) float Aux[2048];
    int t = threadIdx.x;
    int b = blockIdx.y;
    int p0 = blockIdx.x * 64;
    int h = p0 >> 7, w0 = p0 & 127;
    int lane = t & 63, wv = t >> 6;

    // ---- P0: S tile via 16-mode inverse w-DFT, pack into Bb ----
    {
        int wl = lane, cq = wv;
        int w = w0 + wl;
        float cr[16], ci[16];
        #pragma unroll
        for (int ky = 0; ky < 16; ++ky) {
            cr[ky] = tabI[ky * 256 + w * 2];
            ci[ky] = tabI[ky * 256 + w * 2 + 1];
        }
        for (int half = 0; half < 2; ++half) {
            int c0 = half * 64;
            __syncthreads();
            #pragma unroll
            for (int k = 0; k < 8; ++k) {
                int idx = k * 256 + t;
                int ky = (idx & 31) >> 1;
                float g = (ky == 0 ? 1.0f : 2.0f) * (1.0f / 16384.0f);
                Aux[idx] = Zbuf[((size_t)(b * 128 + c0 + (idx >> 5)) * 128 + h) * 32 + (idx & 31)] * g;
            }
            __syncthreads();
            float sv[16];
            #pragma unroll
            for (int j = 0; j < 16; ++j) {
                int cl = cq * 16 + j;
                const float4* zp = (const float4*)(Aux + cl * 32);
                float a = 0.f;
                #pragma unroll
                for (int kk = 0; kk < 8; ++kk) {
                    float4 z = zp[kk];
                    a += z.x * cr[2 * kk] + z.y * ci[2 * kk]
                       + z.z * cr[2 * kk + 1] + z.w * ci[2 * kk + 1];
                }
                sv[j] = a;
            }
            int k0 = c0 + cq * 16;
            pack_write8(Bb, wl, k0, sv);
            pack_write8(Bb, wl, k0 + 8, sv + 8);
        }
    }
    __syncthreads();

    f4v acc[2][4];
    #pragma unroll
    for (int oi = 0; oi < 2; ++oi)
        #pragma unroll
        for (int pt = 0; pt < 4; ++pt) acc[oi][pt] = (f4v){0.f, 0.f, 0.f, 0.f};

    // ---- P1: acc = W1 . S ----
    gemm_step(Bb, w1p, lane, wv, acc);
    __syncthreads();                       // all S reads done

    // issue x prefetch (32 dword loads; land during P2)
    float xr[32];
    #pragma unroll
    for (int pp = 0; pp < 4; ++pp)
        #pragma unroll
        for (int j = 0; j < 8; ++j)
            xr[pp * 8 + j] = xin[((size_t)(b * 128 + pp * 32 + wv * 8 + j)) * 16384 + p0 + lane];

    // Mid = gelu(acc + b1) -> overwrite Bb
    #pragma unroll
    for (int oi = 0; oi < 2; ++oi) {
        int o0 = wv * 32 + oi * 16 + ((lane >> 4) << 2);
        float bv[4];
        #pragma unroll
        for (int r = 0; r < 4; ++r) bv[r] = b1[o0 + r];
        #pragma unroll
        for (int pt = 0; pt < 4; ++pt) {
            int px = pt * 16 + (lane & 15);
            s4v h4, l4;
            #pragma unroll
            for (int r = 0; r < 4; ++r) {
                unsigned short hh, ll;
                split_bf16(gelu_f(acc[oi][pt][r] + bv[r]), hh, ll);
                h4[r] = (short)hh; l4[r] = (short)ll;
            }
            int byt = px * 256 + ((o0 * 2) ^ ((px & 7) << 4));
            *(s4v*)(Bb + byt) = h4;
            *(s4v*)(Bb + 16384 + byt) = l4;
            acc[oi][pt] = (f4v){0.f, 0.f, 0.f, 0.f};
        }
    }
    __syncthreads();

    // ---- P2: acc = W2 . Mid ----
    gemm_step(Bb, w2p, lane, wv, acc);
    __syncthreads();                       // all Mid reads done

    // ---- P3: pack prefetched x, then acc += Wsk . x ----
    #pragma unroll
    for (int pp = 0; pp < 4; ++pp)
        pack_write8(Bb, lane, pp * 32 + wv * 8, &xr[pp * 8]);
    __syncthreads();
    gemm_step(Bb, wskp, lane, wv, acc);

    // ---- epilogue: in-place write ----
    #pragma unroll
    for (int oi = 0; oi < 2; ++oi) {
        int o0 = wv * 32 + oi * 16 + ((lane >> 4) << 2);
        float bv[4];
        #pragma unroll
        for (int r = 0; r < 4; ++r) bv[r] = b2[o0 + r] + bsk[o0 + r];
        #pragma unroll
        for (int pt = 0; pt < 4; ++pt) {
            int px = pt * 16 + (lane & 15);
            #pragma unroll
            for (int r = 0; r < 4; ++r) {
                float xv = acc[oi][pt][r] + bv[r];
                if (ACT) xv = gelu_f(xv);
                xout[((size_t)(b * 128 + o0 + r)) * 16384 + p0 + px] = xv;
            }
        }
    }
}

// ---------------- fused projection ----------------
__global__ __launch_bounds__(256) void k_proj(const float* __restrict__ xin,
        const unsigned short* __restrict__ wap, const float* __restrict__ ba,
        const float* __restrict__ wb, const float* __restrict__ bb,
        float* __restrict__ outp) {
    __shared__ __align__(16) char Bb[32768];
    __shared__ float Red[256];
    int t = threadIdx.x;
    int b = blockIdx.y;
    int p0 = blockIdx.x * 64;
    int lane = t & 63, wv = t >> 6;

    float xr[32];
    #pragma unroll
    for (int pp = 0; pp < 4; ++pp)
        #pragma unroll
        for (int j = 0; j < 8; ++j)
            xr[pp * 8 + j] = xin[((size_t)(b * 128 + pp * 32 + wv * 8 + j)) * 16384 + p0 + lane];
    #pragma unroll
    for (int pp = 0; pp < 4; ++pp)
        pack_write8(Bb, lane, pp * 32 + wv * 8, &xr[pp * 8]);
    __syncthreads();

    f4v acc[2][4];
    #pragma unroll
    for (int oi = 0; oi < 2; ++oi)
        #pragma unroll
        for (int pt = 0; pt < 4; ++pt) acc[oi][pt] = (f4v){0.f, 0.f, 0.f, 0.f};
    gemm_step(Bb, wap, lane, wv, acc);

    float pxsum[4] = {0.f, 0.f, 0.f, 0.f};
    #pragma unroll
    for (int oi = 0; oi < 2; ++oi) {
        int o0 = wv * 32 + oi * 16 + ((lane >> 4) << 2);
        #pragma unroll
        for (int r = 0; r < 4; ++r) {
            float bav = ba[o0 + r];
            float wbv = wb[o0 + r];
            #pragma unroll
            for (int pt = 0; pt < 4; ++pt)
                pxsum[pt] += wbv * gelu_f(acc[oi][pt][r] + bav);
        }
    }
    #pragma unroll
    for (int pt = 0; pt < 4; ++pt) {
        float v = pxsum[pt];
        v += __shfl_xor(v, 16);
        v += __shfl_xor(v, 32);
        if (lane < 16) Red[wv * 64 + pt * 16 + lane] = v;
    }
    __syncthreads();
    if (t < 64)
        outp[(size_t)b * 16384 + p0 + t] = bb[0] + Red[t] + Red[64 + t] + Red[128 + t] + Red[192 + t];
}

extern "C" void kernel_launch(void* const* d_in, const int* in_sizes, int n_in,
                              void* d_out, int out_size, void* d_ws, size_t ws_size,
                              hipStream_t stream) {
    (void)in_sizes; (void)n_in; (void)out_size; (void)ws_size;
    const float* x     = (const float*)d_in[0];
    const float* w1r   = (const float*)d_in[1];
    const float* w1i   = (const float*)d_in[2];
    const float* w2r   = (const float*)d_in[3];
    const float* w2i   = (const float*)d_in[4];
    const float* mlp1w = (const float*)d_in[5];
    const float* mlp1b = (const float*)d_in[6];
    const float* mlp2w = (const float*)d_in[7];
    const float* mlp2b = (const float*)d_in[8];
    const float* wsw   = (const float*)d_in[9];
    const float* wsb   = (const float*)d_in[10];
    const float* fc0w  = (const float*)d_in[11];
    const float* fc0b  = (const float*)d_in[12];
    const float* fc1aw = (const float*)d_in[13];
    const float* fc1ab = (const float*)d_in[14];
    const float* fc1bw = (const float*)d_in[15];
    const float* fc1bb = (const float*)d_in[16];
    float* out = (float*)d_out;

    float* ws   = (float*)d_ws;
    float* xA   = ws;                        // 33,554,432
    float* T    = ws + 33554432;             //  8,388,608
    float* F    = T + 8388608;               //  2,097,152
    float* G    = F + 2097152;               //  2,097,152
    float* tabH = G + 2097152;               //  8192
    float* tabI = tabH + 8192;               //  4096
    unsigned short* wpack = (unsigned short*)(tabI + 4096);  // 13*32768 ushort
    unsigned short* efp   = wpack + 13 * 32768;              // 8192 ushort

    k_init_tables<<<32, 256, 0, stream>>>(tabH, tabI);
    k_pack_w<<<832, 256, 0, stream>>>(mlp1w, mlp2w, wsw, fc1aw, wpack);
    k_pack_ef<<<16, 256, 0, stream>>>(efp);
    k_lift<<<131072, 256, 0, stream>>>(x, fc0w, fc0b, xA);

    for (int l = 0; l < 4; ++l) {
        k_dft_w2<<<4096, 256, 0, stream>>>(xA, T, efp);
        k_dft_h<<<2048, 256, 0, stream>>>(T, F, tabH);
        k_modemix<<<dim3(8, 32, 2), 256, 0, stream>>>(F, G,
            w1r + (size_t)l * 4194304, w1i + (size_t)l * 4194304,
            w2r + (size_t)l * 4194304, w2i + (size_t)l * 4194304);
        k_idft_h<<<2048, 256, 0, stream>>>(G, T, tabH);
        const unsigned short* w1p  = wpack + (size_t)l * 32768;
        const unsigned short* w2p  = wpack + (size_t)(4 + l) * 32768;
        const unsigned short* wskp = wpack + (size_t)(8 + l) * 32768;
        if (l < 3)
            k_layer<1><<<dim3(256, 16), 256, 0, stream>>>(T, xA,
                w1p, mlp1b + l * 128, w2p, mlp2b + l * 128,
                wskp, wsb + l * 128, tabI, xA);
        else
            k_layer<0><<<dim3(256, 16), 256, 0, stream>>>(T, xA,
                w1p, mlp1b + l * 128, w2p, mlp2b + l * 128,
                wskp, wsb + l * 128, tabI, xA);
    }
    k_proj<<<dim3(256, 16), 256, 0, stream>>>(xA, wpack + (size_t)12 * 32768,
        fc1ab, fc1bw, fc1bb, out);
}

// Round 5
// 1491.005 us; speedup vs baseline: 2.8371x; 1.3965x over previous
//
#include <hip/hip_runtime.h>
#include <math.h>

#define PI_F 3.14159265358979323846f

typedef __attribute__((ext_vector_type(8))) short s8v;
typedef __attribute__((ext_vector_type(4))) short s4v;
typedef __attribute__((ext_vector_type(4))) float f4v;

#define MFMA16(a, b, c) __builtin_amdgcn_mfma_f32_16x16x32_bf16(a, b, c, 0, 0, 0)

// fast erf, A&S 7.1.26, |err| <= 1.5e-7
__device__ __forceinline__ float erf_f(float x) {
    float a = fabsf(x);
    float t = 1.0f / fmaf(0.3275911f, a, 1.0f);
    float p = t * fmaf(t, fmaf(t, fmaf(t, fmaf(t, 1.061405429f, -1.453152027f),
                1.421413741f), -0.284496736f), 0.254829592f);
    float r = 1.0f - p * __expf(-a * a);
    return copysignf(r, x);
}
__device__ __forceinline__ float gelu_f(float x) {
    return 0.5f * x * (1.0f + erf_f(x * 0.70710678118654752440f));
}

__device__ __forceinline__ unsigned bf16_rn_bits(float x) {
    unsigned u = __builtin_bit_cast(unsigned, x);
    return (u + 0x7FFFu + ((u >> 16) & 1u)) & 0xFFFF0000u;
}
__device__ __forceinline__ void split_bf16(float x, unsigned short& h, unsigned short& l) {
    unsigned hb = bf16_rn_bits(x);
    float hf = __builtin_bit_cast(float, hb);
    h = (unsigned short)(hb >> 16);
    l = (unsigned short)(bf16_rn_bits(x - hf) >> 16);
}

// pack 8 fp32 (consecutive k, k0 mult of 8) into swizzled hi/lo LDS B-buffer
// layout: [px 0..63][k 0..127] bf16, hi @0, lo @16384; byte ^= ((px&7)<<4)
__device__ __forceinline__ void pack_write8(char* Bb, int px, int k0, const float* v) {
    s8v hv, lv;
    #pragma unroll
    for (int j = 0; j < 8; ++j) {
        unsigned short h, l;
        split_bf16(v[j], h, l);
        hv[j] = (short)h; lv[j] = (short)l;
    }
    int byt = px * 256 + ((k0 * 2) ^ ((px & 7) << 4));
    *(s8v*)(Bb + byt) = hv;
    *(s8v*)(Bb + 16384 + byt) = lv;
}

// 128(o) x 64(px) x 32*KCN(k) GEMM accumulate via split-bf16 MFMA, kc in [KC0,KC0+KCN)
template<int KC0, int KCN>
__device__ __forceinline__ void gemm_range(const char* Bb, const unsigned short* wp,
                                           int lane, int wv, f4v acc[2][4]) {
    #pragma unroll
    for (int kc = KC0; kc < KC0 + KCN; ++kc) {
        s8v bh[4], bl[4];
        int k0 = kc * 32 + ((lane >> 4) << 3);
        #pragma unroll
        for (int pt = 0; pt < 4; ++pt) {
            int px = pt * 16 + (lane & 15);
            int byt = px * 256 + ((k0 * 2) ^ ((px & 7) << 4));
            bh[pt] = *(const s8v*)(Bb + byt);
            bl[pt] = *(const s8v*)(Bb + 16384 + byt);
        }
        #pragma unroll
        for (int oi = 0; oi < 2; ++oi) {
            const unsigned short* ap = wp + (wv * 2 + oi) * 2048 + kc * 512 + lane * 8;
            s8v ah = *(const s8v*)ap;
            s8v al = *(const s8v*)(ap + 16384);
            #pragma unroll
            for (int pt = 0; pt < 4; ++pt) {
                acc[oi][pt] = MFMA16(ah, bh[pt], acc[oi][pt]);
                acc[oi][pt] = MFMA16(ah, bl[pt], acc[oi][pt]);
                acc[oi][pt] = MFMA16(al, bh[pt], acc[oi][pt]);
            }
        }
    }
}

// ---------------- weight pre-split+pack: 13 fp32 128x128 mats ----------------
__global__ __launch_bounds__(256) void k_pack_w(const float* __restrict__ mlp1w,
        const float* __restrict__ mlp2w, const float* __restrict__ wsw,
        const float* __restrict__ fc1aw, unsigned short* __restrict__ wpack) {
    int idx = blockIdx.x * 256 + threadIdx.x;
    if (idx >= 212992) return;           // 13 * 16384
    int mat = idx >> 14, e = idx & 16383;
    const float* src = mat < 4  ? mlp1w + mat * 16384 + e
                     : mat < 8  ? mlp2w + (mat - 4) * 16384 + e
                     : mat < 12 ? wsw + (mat - 8) * 16384 + e
                                : fc1aw + e;
    float x = *src;
    unsigned short h, l;
    split_bf16(x, h, l);
    int o = e >> 7, i = e & 127;
    int pos = (o >> 4) * 2048 + (i >> 5) * 512 + (((i >> 3) & 3) * 16 + (o & 15)) * 8 + (i & 7);
    wpack[(size_t)mat * 32768 + pos] = h;
    wpack[(size_t)mat * 32768 + 16384 + pos] = l;
}

// ---------------- twiddle fragment tables ----------------
// efp: forward-w DFT B-frags [kc4][nt2][lane64][j8], hi @0, lo @4096 (ushort)
// ef2: inverse-w DFT B-frags [wt8][lane64][j8], hi @0, lo @4096; value includes
//      irfft scale g(ky)/HW:  E2[q][w] = g * (q&1 ? -sin : cos)(2pi ky w / 128)
__global__ void k_pack_ef(unsigned short* __restrict__ efp,
                          unsigned short* __restrict__ ef2) {
    int t = blockIdx.x * 256 + threadIdx.x;
    if (t < 4096) {
        int j = t & 7, lane = (t >> 3) & 63, nt = (t >> 9) & 1, kc = t >> 10;
        int w = kc * 32 + ((lane >> 4) << 3) + j;
        int q = nt * 16 + (lane & 15);
        int ky = q >> 1, c = q & 1;
        int m = (ky * w) & 127;
        float th = (2.0f * PI_F / 128.0f) * (float)m;
        float v = c ? -sinf(th) : cosf(th);
        unsigned short h, l;
        split_bf16(v, h, l);
        efp[t] = h;
        efp[4096 + t] = l;
    }
    if (t < 4096) {
        int j = t & 7, lane = (t >> 3) & 63, wt = t >> 9;
        int w = wt * 16 + (lane & 15);
        int q = ((lane >> 4) << 3) + j;
        int ky = q >> 1, c = q & 1;
        float g = (ky == 0 ? 1.0f : 2.0f) * (1.0f / 16384.0f);
        int m = (ky * w) & 127;
        float th = (2.0f * PI_F / 128.0f) * (float)m;
        float v = (c ? -sinf(th) : cosf(th)) * g;
        unsigned short h, l;
        split_bf16(v, h, l);
        ef2[t] = h;
        ef2[4096 + t] = l;
    }
}

// ---------------- tabH for h-DFTs ----------------
__global__ void k_init_tables(float* __restrict__ tabH) {
    int idx = blockIdx.x * 256 + threadIdx.x;
    if (idx < 8192) {
        int c = idx & 1, kxi = (idx >> 1) & 31, h = idx >> 6;
        int f = kxi < 16 ? kxi : kxi - 32;
        int m = ((f * h) % 128 + 128) & 127;
        float th = (2.0f * PI_F / 128.0f) * (float)m;
        tabH[idx] = c ? -sinf(th) : cosf(th);
    }
}

// ---------------- lifting (4 px / thread, float4) ----------------
__global__ __launch_bounds__(256) void k_lift(const float* __restrict__ xin,
        const float* __restrict__ w0, const float* __restrict__ b0,
        float* __restrict__ xout) {
    int idx = blockIdx.x * 256 + threadIdx.x;     // 8,388,608 quads
    int wq = idx & 31, h = (idx >> 5) & 127, c = (idx >> 12) & 127, b = idx >> 19;
    const float4* xp = (const float4*)(xin + ((size_t)(b * 128 + h) * 128 + wq * 4) * 2);
    float4 p01 = xp[0], p23 = xp[1];
    float wa = w0[c], wbv = w0[128 + c], wg = w0[256 + c], wd = w0[384 + c];
    float base = (float)h * (1.0f / 127.0f) * wg + b0[c];
    float ws = (1.0f / 127.0f) * wd;
    float4 v;
    v.x = p01.x * wa + p01.y * wbv + (float)(wq * 4 + 0) * ws + base;
    v.y = p01.z * wa + p01.w * wbv + (float)(wq * 4 + 1) * ws + base;
    v.z = p23.x * wa + p23.y * wbv + (float)(wq * 4 + 2) * ws + base;
    v.w = p23.z * wa + p23.w * wbv + (float)(wq * 4 + 3) * ws + base;
    *(float4*)(xout + ((size_t)(b * 128 + c) * 128 + h) * 128 + wq * 4) = v;
}

// ---------------- forward DFT along w via MFMA: x -> T(B,C,H,16)cplx ----------
__global__ __launch_bounds__(256) void k_dft_w2(const float* __restrict__ x,
        float* __restrict__ T, const unsigned short* __restrict__ efp) {
    __shared__ __align__(16) char Xb[32768];
    int t = threadIdx.x;
    size_t r0 = (size_t)blockIdx.x * 64;     // 64 rows (b,c,h)
    const float4* xg = (const float4*)(x + r0 * 128);
    #pragma unroll
    for (int k = 0; k < 8; ++k) {
        int idx4 = k * 256 + t;
        float4 f = xg[idx4];
        int row = idx4 >> 5;
        int w0 = (idx4 & 31) * 4;
        s4v h4, l4;
        const float* fp = (const float*)&f;
        #pragma unroll
        for (int q = 0; q < 4; ++q) {
            unsigned short hh, ll;
            split_bf16(fp[q], hh, ll);
            h4[q] = (short)hh; l4[q] = (short)ll;
        }
        int byt = row * 256 + ((w0 * 2) ^ ((row & 7) << 4));
        *(s4v*)(Xb + byt) = h4;
        *(s4v*)(Xb + 16384 + byt) = l4;
    }
    __syncthreads();
    int lane = t & 63, wv = t >> 6;
    f4v acc[2];
    acc[0] = (f4v){0.f, 0.f, 0.f, 0.f};
    acc[1] = (f4v){0.f, 0.f, 0.f, 0.f};
    #pragma unroll
    for (int kc = 0; kc < 4; ++kc) {
        int row = wv * 16 + (lane & 15);
        int k0 = kc * 32 + ((lane >> 4) << 3);
        int byt = row * 256 + ((k0 * 2) ^ ((row & 7) << 4));
        s8v ah = *(const s8v*)(Xb + byt);
        s8v al = *(const s8v*)(Xb + 16384 + byt);
        #pragma unroll
        for (int nt = 0; nt < 2; ++nt) {
            const unsigned short* bp = efp + ((kc * 2 + nt) * 64 + lane) * 8;
            s8v bh = *(const s8v*)bp;
            s8v bl = *(const s8v*)(bp + 4096);
            acc[nt] = MFMA16(ah, bh, acc[nt]);
            acc[nt] = MFMA16(ah, bl, acc[nt]);
            acc[nt] = MFMA16(al, bh, acc[nt]);
        }
    }
    #pragma unroll
    for (int nt = 0; nt < 2; ++nt)
        #pragma unroll
        for (int r = 0; r < 4; ++r)
            T[(r0 + wv * 16 + (lane >> 4) * 4 + r) * 32 + nt * 16 + (lane & 15)] = acc[nt][r];
}

// ---------------- forward DFT along h ----------------
__global__ __launch_bounds__(256) void k_dft_h(const float* __restrict__ T,
        float* __restrict__ F, const float* __restrict__ tabH) {
    __shared__ float Ts[4096];
    __shared__ float Eh[8192];
    int t = threadIdx.x, bi = blockIdx.x;
    #pragma unroll
    for (int k = 0; k < 32; ++k) Eh[k * 256 + t] = tabH[k * 256 + t];
    const float* Tp = T + (size_t)bi * 4096;
    #pragma unroll
    for (int k = 0; k < 16; ++k) Ts[k * 256 + t] = Tp[k * 256 + t];
    __syncthreads();
    int kxi = t & 31, g = t >> 5;
    int ky0 = g * 2;
    float ar0 = 0.f, ai0 = 0.f, ar1 = 0.f, ai1 = 0.f;
    for (int h = 0; h < 128; ++h) {
        float er = Eh[h * 64 + kxi * 2], ei = Eh[h * 64 + kxi * 2 + 1];
        float tr0 = Ts[h * 32 + ky0 * 2],     ti0 = Ts[h * 32 + ky0 * 2 + 1];
        float tr1 = Ts[h * 32 + ky0 * 2 + 2], ti1 = Ts[h * 32 + ky0 * 2 + 3];
        ar0 += tr0 * er - ti0 * ei;  ai0 += tr0 * ei + ti0 * er;
        ar1 += tr1 * er - ti1 * ei;  ai1 += tr1 * ei + ti1 * er;
    }
    *(float4*)(F + (size_t)bi * 1024 + (kxi * 16 + ky0) * 2) = make_float4(ar0, ai0, ar1, ai1);
}

// ---------------- per-mode complex C x C mix (b-split over z) ----------------
__global__ __launch_bounds__(256) void k_modemix(const float* __restrict__ F,
        float* __restrict__ G,
        const float* __restrict__ w1r, const float* __restrict__ w1i,
        const float* __restrict__ w2r, const float* __restrict__ w2i) {
    int t = threadIdx.x;
    int m = blockIdx.x * 64 + (t & 63);
    int o = blockIdx.y * 4 + (t >> 6);
    int b0 = blockIdx.z * 8;
    const float* wrp = (m < 256) ? w1r : w2r;
    const float* wip = (m < 256) ? w1i : w2i;
    int ms = m & 255;
    float accr[8], acci[8];
    #pragma unroll
    for (int b = 0; b < 8; ++b) { accr[b] = 0.f; acci[b] = 0.f; }
    #pragma unroll 2
    for (int i = 0; i < 128; ++i) {
        float wr = wrp[(i * 128 + o) * 256 + ms];
        float wi = wip[(i * 128 + o) * 256 + ms];
        const float* Fp = F + i * 1024 + m * 2 + (size_t)b0 * 131072;
        #pragma unroll
        for (int b = 0; b < 8; ++b) {
            float fr = Fp[b * 131072];
            float fi = Fp[b * 131072 + 1];
            accr[b] += fr * wr - fi * wi;
            acci[b] += fr * wi + fi * wr;
        }
    }
    #pragma unroll
    for (int b = 0; b < 8; ++b) {
        float* Gp = G + ((size_t)((b0 + b) * 128 + o) * 512 + m) * 2;
        Gp[0] = accr[b]; Gp[1] = acci[b];
    }
}

// ---------------- inverse DFT along h ----------------
__global__ __launch_bounds__(256) void k_idft_h(const float* __restrict__ G,
        float* __restrict__ Z, const float* __restrict__ tabH) {
    __shared__ float Gs[1024];
    __shared__ float Eh[8192];
    int t = threadIdx.x, bo = blockIdx.x;
    #pragma unroll
    for (int k = 0; k < 32; ++k) Eh[k * 256 + t] = tabH[k * 256 + t];
    const float* Gp = G + (size_t)bo * 1024;
    #pragma unroll
    for (int k = 0; k < 4; ++k) Gs[k * 256 + t] = Gp[k * 256 + t];
    __syncthreads();
    int ky = t & 15, hb = t >> 4;
    float zr[8], zi[8];
    #pragma unroll
    for (int j = 0; j < 8; ++j) { zr[j] = 0.f; zi[j] = 0.f; }
    for (int kxi = 0; kxi < 32; ++kxi) {
        float gr = Gs[(kxi * 16 + ky) * 2], gi = Gs[(kxi * 16 + ky) * 2 + 1];
        #pragma unroll
        for (int j = 0; j < 8; ++j) {
            int h = hb + 16 * j;
            float c = Eh[h * 64 + kxi * 2], s = Eh[h * 64 + kxi * 2 + 1];
            zr[j] += gr * c + gi * s;
            zi[j] += gi * c - gr * s;
        }
    }
    float* Zp = Z + (size_t)bo * 4096;
    #pragma unroll
    for (int j = 0; j < 8; ++j) {
        int h = hb + 16 * j;
        Zp[h * 32 + ky * 2] = zr[j];
        Zp[h * 32 + ky * 2 + 1] = zi[j];
    }
}

// ---------------- fused layer tail: Z -> S (MFMA idft_w) -> MLP + skip, in-place ----
template<int ACT>
__global__ __launch_bounds__(256, 3) void k_layer(
    const float* __restrict__ Zbuf, const float* __restrict__ xin,
    const unsigned short* __restrict__ w1p, const float* __restrict__ b1,
    const unsigned short* __restrict__ w2p, const float* __restrict__ b2,
    const unsigned short* __restrict__ wskp, const float* __restrict__ bsk,
    const unsigned short* __restrict__ ef2, float* __restrict__ xout)
{
    __shared__ __align__(16) char Bb[32768];
    int t = threadIdx.x;
    int b = blockIdx.y;
    int p0 = blockIdx.x * 64;
    int h = p0 >> 7, w0 = p0 & 127;
    int lane = t & 63, wv = t >> 6;

    // ---- P0: S = Z . E2 via MFMA (K=32), pack C-frags into Bb ----
    {
        int q0 = (lane >> 4) << 3;
        s8v zah[2], zal[2];
        #pragma unroll
        for (int ct = 0; ct < 2; ++ct) {
            int c = wv * 32 + ct * 16 + (lane & 15);
            const float* zp = Zbuf + ((size_t)(b * 128 + c) * 128 + h) * 32 + q0;
            float4 z0 = *(const float4*)zp;
            float4 z1 = *(const float4*)(zp + 4);
            float zv[8] = {z0.x, z0.y, z0.z, z0.w, z1.x, z1.y, z1.z, z1.w};
            #pragma unroll
            for (int j = 0; j < 8; ++j) {
                unsigned short hh, ll;
                split_bf16(zv[j], hh, ll);
                zah[ct][j] = (short)hh; zal[ct][j] = (short)ll;
            }
        }
        int wtg0 = w0 >> 4;
        #pragma unroll
        for (int wt = 0; wt < 4; ++wt) {
            const unsigned short* bp = ef2 + ((wtg0 + wt) * 64 + lane) * 8;
            s8v bh = *(const s8v*)bp;
            s8v bl = *(const s8v*)(bp + 4096);
            #pragma unroll
            for (int ct = 0; ct < 2; ++ct) {
                f4v c4 = (f4v){0.f, 0.f, 0.f, 0.f};
                c4 = MFMA16(zah[ct], bh, c4);
                c4 = MFMA16(zah[ct], bl, c4);
                c4 = MFMA16(zal[ct], bh, c4);
                int px = wt * 16 + (lane & 15);
                int c0 = wv * 32 + ct * 16 + ((lane >> 4) << 2);
                s4v h4, l4;
                #pragma unroll
                for (int r = 0; r < 4; ++r) {
                    unsigned short hh, ll;
                    split_bf16(c4[r], hh, ll);
                    h4[r] = (short)hh; l4[r] = (short)ll;
                }
                int byt = px * 256 + ((c0 * 2) ^ ((px & 7) << 4));
                *(s4v*)(Bb + byt) = h4;
                *(s4v*)(Bb + 16384 + byt) = l4;
            }
        }
    }
    __syncthreads();

    f4v acc[2][4];
    #pragma unroll
    for (int oi = 0; oi < 2; ++oi)
        #pragma unroll
        for (int pt = 0; pt < 4; ++pt) acc[oi][pt] = (f4v){0.f, 0.f, 0.f, 0.f};

    // ---- P1: acc = W1 . S ----
    gemm_range<0, 4>(Bb, w1p, lane, wv, acc);
    __syncthreads();                       // all S reads done

    // issue x prefetch half 0 (channels 0..63); lands during Mid-pack + P2
    float xr[16];
    #pragma unroll
    for (int j = 0; j < 16; ++j)
        xr[j] = xin[((size_t)(b * 128 + wv * 16 + j)) * 16384 + p0 + lane];

    // Mid = gelu(acc + b1) -> overwrite Bb
    #pragma unroll
    for (int oi = 0; oi < 2; ++oi) {
        int o0 = wv * 32 + oi * 16 + ((lane >> 4) << 2);
        float bv[4];
        #pragma unroll
        for (int r = 0; r < 4; ++r) bv[r] = b1[o0 + r];
        #pragma unroll
        for (int pt = 0; pt < 4; ++pt) {
            int px = pt * 16 + (lane & 15);
            s4v h4, l4;
            #pragma unroll
            for (int r = 0; r < 4; ++r) {
                unsigned short hh, ll;
                split_bf16(gelu_f(acc[oi][pt][r] + bv[r]), hh, ll);
                h4[r] = (short)hh; l4[r] = (short)ll;
            }
            int byt = px * 256 + ((o0 * 2) ^ ((px & 7) << 4));
            *(s4v*)(Bb + byt) = h4;
            *(s4v*)(Bb + 16384 + byt) = l4;
            acc[oi][pt] = (f4v){0.f, 0.f, 0.f, 0.f};
        }
    }
    __syncthreads();

    // ---- P2: acc = W2 . Mid ----
    gemm_range<0, 4>(Bb, w2p, lane, wv, acc);
    __syncthreads();                       // all Mid reads done

    // ---- P3: skip GEMM in two K-halves, packing one half while computing the other ----
    pack_write8(Bb, lane, wv * 16, xr);
    pack_write8(Bb, lane, wv * 16 + 8, xr + 8);
    #pragma unroll
    for (int j = 0; j < 16; ++j)           // half 1 (channels 64..127)
        xr[j] = xin[((size_t)(b * 128 + 64 + wv * 16 + j)) * 16384 + p0 + lane];
    __syncthreads();
    gemm_range<0, 2>(Bb, wskp, lane, wv, acc);
    pack_write8(Bb, lane, 64 + wv * 16, xr);
    pack_write8(Bb, lane, 64 + wv * 16 + 8, xr + 8);
    __syncthreads();
    gemm_range<2, 2>(Bb, wskp, lane, wv, acc);

    // ---- epilogue: in-place write ----
    #pragma unroll
    for (int oi = 0; oi < 2; ++oi) {
        int o0 = wv * 32 + oi * 16 + ((lane >> 4) << 2);
        float bv[4];
        #pragma unroll
        for (int r = 0; r < 4; ++r) bv[r] = b2[o0 + r] + bsk[o0 + r];
        #pragma unroll
        for (int pt = 0; pt < 4; ++pt) {
            int px = pt * 16 + (lane & 15);
            #pragma unroll
            for (int r = 0; r < 4; ++r) {
                float xv = acc[oi][pt][r] + bv[r];
                if (ACT) xv = gelu_f(xv);
                xout[((size_t)(b * 128 + o0 + r)) * 16384 + p0 + px] = xv;
            }
        }
    }
}

// ---------------- fused projection ----------------
__global__ __launch_bounds__(256) void k_proj(const float* __restrict__ xin,
        const unsigned short* __restrict__ wap, const float* __restrict__ ba,
        const float* __restrict__ wb, const float* __restrict__ bb,
        float* __restrict__ outp) {
    __shared__ __align__(16) char Bb[32768];
    __shared__ float Red[256];
    int t = threadIdx.x;
    int b = blockIdx.y;
    int p0 = blockIdx.x * 64;
    int lane = t & 63, wv = t >> 6;

    float xr[16];
    #pragma unroll
    for (int j = 0; j < 16; ++j)
        xr[j] = xin[((size_t)(b * 128 + wv * 16 + j)) * 16384 + p0 + lane];
    pack_write8(Bb, lane, wv * 16, xr);
    pack_write8(Bb, lane, wv * 16 + 8, xr + 8);
    #pragma unroll
    for (int j = 0; j < 16; ++j)
        xr[j] = xin[((size_t)(b * 128 + 64 + wv * 16 + j)) * 16384 + p0 + lane];
    pack_write8(Bb, lane, 64 + wv * 16, xr);
    pack_write8(Bb, lane, 64 + wv * 16 + 8, xr + 8);
    __syncthreads();

    f4v acc[2][4];
    #pragma unroll
    for (int oi = 0; oi < 2; ++oi)
        #pragma unroll
        for (int pt = 0; pt < 4; ++pt) acc[oi][pt] = (f4v){0.f, 0.f, 0.f, 0.f};
    gemm_range<0, 4>(Bb, wap, lane, wv, acc);

    float pxsum[4] = {0.f, 0.f, 0.f, 0.f};
    #pragma unroll
    for (int oi = 0; oi < 2; ++oi) {
        int o0 = wv * 32 + oi * 16 + ((lane >> 4) << 2);
        #pragma unroll
        for (int r = 0; r < 4; ++r) {
            float bav = ba[o0 + r];
            float wbv = wb[o0 + r];
            #pragma unroll
            for (int pt = 0; pt < 4; ++pt)
                pxsum[pt] += wbv * gelu_f(acc[oi][pt][r] + bav);
        }
    }
    #pragma unroll
    for (int pt = 0; pt < 4; ++pt) {
        float v = pxsum[pt];
        v += __shfl_xor(v, 16);
        v += __shfl_xor(v, 32);
        if (lane < 16) Red[wv * 64 + pt * 16 + lane] = v;
    }
    __syncthreads();
    if (t < 64)
        outp[(size_t)b * 16384 + p0 + t] = bb[0] + Red[t] + Red[64 + t] + Red[128 + t] + Red[192 + t];
}

extern "C" void kernel_launch(void* const* d_in, const int* in_sizes, int n_in,
                              void* d_out, int out_size, void* d_ws, size_t ws_size,
                              hipStream_t stream) {
    (void)in_sizes; (void)n_in; (void)out_size; (void)ws_size;
    const float* x     = (const float*)d_in[0];
    const float* w1r   = (const float*)d_in[1];
    const float* w1i   = (const float*)d_in[2];
    const float* w2r   = (const float*)d_in[3];
    const float* w2i   = (const float*)d_in[4];
    const float* mlp1w = (const float*)d_in[5];
    const float* mlp1b = (const float*)d_in[6];
    const float* mlp2w = (const float*)d_in[7];
    const float* mlp2b = (const float*)d_in[8];
    const float* wsw   = (const float*)d_in[9];
    const float* wsb   = (const float*)d_in[10];
    const float* fc0w  = (const float*)d_in[11];
    const float* fc0b  = (const float*)d_in[12];
    const float* fc1aw = (const float*)d_in[13];
    const float* fc1ab = (const float*)d_in[14];
    const float* fc1bw = (const float*)d_in[15];
    const float* fc1bb = (const float*)d_in[16];
    float* out = (float*)d_out;

    float* ws   = (float*)d_ws;
    float* xA   = ws;                        // 33,554,432
    float* T    = ws + 33554432;             //  8,388,608
    float* F    = T + 8388608;               //  2,097,152
    float* G    = F + 2097152;               //  2,097,152
    float* tabH = G + 2097152;               //  8192
    unsigned short* wpack = (unsigned short*)(tabH + 8192);  // 13*32768 ushort
    unsigned short* efp   = wpack + 13 * 32768;              // 8192 ushort
    unsigned short* ef2   = efp + 8192;                      // 8192 ushort

    k_init_tables<<<32, 256, 0, stream>>>(tabH);
    k_pack_w<<<832, 256, 0, stream>>>(mlp1w, mlp2w, wsw, fc1aw, wpack);
    k_pack_ef<<<16, 256, 0, stream>>>(efp, ef2);
    k_lift<<<32768, 256, 0, stream>>>(x, fc0w, fc0b, xA);

    for (int l = 0; l < 4; ++l) {
        k_dft_w2<<<4096, 256, 0, stream>>>(xA, T, efp);
        k_dft_h<<<2048, 256, 0, stream>>>(T, F, tabH);
        k_modemix<<<dim3(8, 32, 2), 256, 0, stream>>>(F, G,
            w1r + (size_t)l * 4194304, w1i + (size_t)l * 4194304,
            w2r + (size_t)l * 4194304, w2i + (size_t)l * 4194304);
        k_idft_h<<<2048, 256, 0, stream>>>(G, T, tabH);
        const unsigned short* w1p  = wpack + (size_t)l * 32768;
        const unsigned short* w2p  = wpack + (size_t)(4 + l) * 32768;
        const unsigned short* wskp = wpack + (size_t)(8 + l) * 32768;
        if (l < 3)
            k_layer<1><<<dim3(256, 16), 256, 0, stream>>>(T, xA,
                w1p, mlp1b + l * 128, w2p, mlp2b + l * 128,
                wskp, wsb + l * 128, ef2, xA);
        else
            k_layer<0><<<dim3(256, 16), 256, 0, stream>>>(T, xA,
                w1p, mlp1b + l * 128, w2p, mlp2b + l * 128,
                wskp, wsb + l * 128, ef2, xA);
    }
    k_proj<<<dim3(256, 16), 256, 0, stream>>>(xA, wpack + (size_t)12 * 32768,
        fc1ab, fc1bw, fc1bb, out);
}

// Round 6
// 1291.411 us; speedup vs baseline: 3.2756x; 1.1546x over previous
//
#include <hip/hip_runtime.h>
#include <math.h>

#define PI_F 3.14159265358979323846f

typedef __attribute__((ext_vector_type(8))) short s8v;
typedef __attribute__((ext_vector_type(4))) short s4v;
typedef __attribute__((ext_vector_type(4))) float f4v;

#define MFMA16(a, b, c) __builtin_amdgcn_mfma_f32_16x16x32_bf16(a, b, c, 0, 0, 0)

// fast erf, A&S 7.1.26, |err| <= 1.5e-7
__device__ __forceinline__ float erf_f(float x) {
    float a = fabsf(x);
    float t = 1.0f / fmaf(0.3275911f, a, 1.0f);
    float p = t * fmaf(t, fmaf(t, fmaf(t, fmaf(t, 1.061405429f, -1.453152027f),
                1.421413741f), -0.284496736f), 0.254829592f);
    float r = 1.0f - p * __expf(-a * a);
    return copysignf(r, x);
}
__device__ __forceinline__ float gelu_f(float x) {
    return 0.5f * x * (1.0f + erf_f(x * 0.70710678118654752440f));
}

__device__ __forceinline__ unsigned bf16_rn_bits(float x) {
    unsigned u = __builtin_bit_cast(unsigned, x);
    return (u + 0x7FFFu + ((u >> 16) & 1u)) & 0xFFFF0000u;
}
__device__ __forceinline__ void split_bf16(float x, unsigned short& h, unsigned short& l) {
    unsigned hb = bf16_rn_bits(x);
    float hf = __builtin_bit_cast(float, hb);
    h = (unsigned short)(hb >> 16);
    l = (unsigned short)(bf16_rn_bits(x - hf) >> 16);
}

// pack 8 fp32 (consecutive k, k0 mult of 8) into swizzled hi/lo LDS B-buffer
// layout: [px 0..63][k 0..127] bf16, hi @0, lo @16384; byte ^= ((px&7)<<4)
__device__ __forceinline__ void pack_write8(char* Bb, int px, int k0, const float* v) {
    s8v hv, lv;
    #pragma unroll
    for (int j = 0; j < 8; ++j) {
        unsigned short h, l;
        split_bf16(v[j], h, l);
        hv[j] = (short)h; lv[j] = (short)l;
    }
    int byt = px * 256 + ((k0 * 2) ^ ((px & 7) << 4));
    *(s8v*)(Bb + byt) = hv;
    *(s8v*)(Bb + 16384 + byt) = lv;
}

// 128(o) x 64(px) x 32*KCN(k) GEMM accumulate via split-bf16 MFMA, kc in [KC0,KC0+KCN)
template<int KC0, int KCN>
__device__ __forceinline__ void gemm_range(const char* Bb, const unsigned short* wp,
                                           int lane, int wv, f4v acc[2][4]) {
    #pragma unroll
    for (int kc = KC0; kc < KC0 + KCN; ++kc) {
        s8v bh[4], bl[4];
        int k0 = kc * 32 + ((lane >> 4) << 3);
        #pragma unroll
        for (int pt = 0; pt < 4; ++pt) {
            int px = pt * 16 + (lane & 15);
            int byt = px * 256 + ((k0 * 2) ^ ((px & 7) << 4));
            bh[pt] = *(const s8v*)(Bb + byt);
            bl[pt] = *(const s8v*)(Bb + 16384 + byt);
        }
        #pragma unroll
        for (int oi = 0; oi < 2; ++oi) {
            const unsigned short* ap = wp + (wv * 2 + oi) * 2048 + kc * 512 + lane * 8;
            s8v ah = *(const s8v*)ap;
            s8v al = *(const s8v*)(ap + 16384);
            #pragma unroll
            for (int pt = 0; pt < 4; ++pt) {
                acc[oi][pt] = MFMA16(ah, bh[pt], acc[oi][pt]);
                acc[oi][pt] = MFMA16(ah, bl[pt], acc[oi][pt]);
                acc[oi][pt] = MFMA16(al, bh[pt], acc[oi][pt]);
            }
        }
    }
}

// ---------------- weight pre-split+pack: 13 fp32 128x128 mats ----------------
__global__ __launch_bounds__(256) void k_pack_w(const float* __restrict__ mlp1w,
        const float* __restrict__ mlp2w, const float* __restrict__ wsw,
        const float* __restrict__ fc1aw, unsigned short* __restrict__ wpack) {
    int idx = blockIdx.x * 256 + threadIdx.x;
    if (idx >= 212992) return;           // 13 * 16384
    int mat = idx >> 14, e = idx & 16383;
    const float* src = mat < 4  ? mlp1w + mat * 16384 + e
                     : mat < 8  ? mlp2w + (mat - 4) * 16384 + e
                     : mat < 12 ? wsw + (mat - 8) * 16384 + e
                                : fc1aw + e;
    float x = *src;
    unsigned short h, l;
    split_bf16(x, h, l);
    int o = e >> 7, i = e & 127;
    int pos = (o >> 4) * 2048 + (i >> 5) * 512 + (((i >> 3) & 3) * 16 + (o & 15)) * 8 + (i & 7);
    wpack[(size_t)mat * 32768 + pos] = h;
    wpack[(size_t)mat * 32768 + 16384 + pos] = l;
}

// ---------------- twiddle fragment tables ----------------
__global__ void k_pack_ef(unsigned short* __restrict__ efp,
                          unsigned short* __restrict__ ef2) {
    int t = blockIdx.x * 256 + threadIdx.x;
    if (t < 4096) {
        int j = t & 7, lane = (t >> 3) & 63, nt = (t >> 9) & 1, kc = t >> 10;
        int w = kc * 32 + ((lane >> 4) << 3) + j;
        int q = nt * 16 + (lane & 15);
        int ky = q >> 1, c = q & 1;
        int m = (ky * w) & 127;
        float th = (2.0f * PI_F / 128.0f) * (float)m;
        float v = c ? -sinf(th) : cosf(th);
        unsigned short h, l;
        split_bf16(v, h, l);
        efp[t] = h;
        efp[4096 + t] = l;
    }
    if (t < 4096) {
        int j = t & 7, lane = (t >> 3) & 63, wt = t >> 9;
        int w = wt * 16 + (lane & 15);
        int q = ((lane >> 4) << 3) + j;
        int ky = q >> 1, c = q & 1;
        float g = (ky == 0 ? 1.0f : 2.0f) * (1.0f / 16384.0f);
        int m = (ky * w) & 127;
        float th = (2.0f * PI_F / 128.0f) * (float)m;
        float v = (c ? -sinf(th) : cosf(th)) * g;
        unsigned short h, l;
        split_bf16(v, h, l);
        ef2[t] = h;
        ef2[4096 + t] = l;
    }
}

// ---------------- tabH for h-DFTs ----------------
__global__ void k_init_tables(float* __restrict__ tabH) {
    int idx = blockIdx.x * 256 + threadIdx.x;
    if (idx < 8192) {
        int c = idx & 1, kxi = (idx >> 1) & 31, h = idx >> 6;
        int f = kxi < 16 ? kxi : kxi - 32;
        int m = ((f * h) % 128 + 128) & 127;
        float th = (2.0f * PI_F / 128.0f) * (float)m;
        tabH[idx] = c ? -sinf(th) : cosf(th);
    }
}

// ---------------- lifting (4 px / thread, float4) ----------------
__global__ __launch_bounds__(256) void k_lift(const float* __restrict__ xin,
        const float* __restrict__ w0, const float* __restrict__ b0,
        float* __restrict__ xout) {
    int idx = blockIdx.x * 256 + threadIdx.x;     // 8,388,608 quads
    int wq = idx & 31, h = (idx >> 5) & 127, c = (idx >> 12) & 127, b = idx >> 19;
    const float4* xp = (const float4*)(xin + ((size_t)(b * 128 + h) * 128 + wq * 4) * 2);
    float4 p01 = xp[0], p23 = xp[1];
    float wa = w0[c], wbv = w0[128 + c], wg = w0[256 + c], wd = w0[384 + c];
    float base = (float)h * (1.0f / 127.0f) * wg + b0[c];
    float ws = (1.0f / 127.0f) * wd;
    float4 v;
    v.x = p01.x * wa + p01.y * wbv + (float)(wq * 4 + 0) * ws + base;
    v.y = p01.z * wa + p01.w * wbv + (float)(wq * 4 + 1) * ws + base;
    v.z = p23.x * wa + p23.y * wbv + (float)(wq * 4 + 2) * ws + base;
    v.w = p23.z * wa + p23.w * wbv + (float)(wq * 4 + 3) * ws + base;
    *(float4*)(xout + ((size_t)(b * 128 + c) * 128 + h) * 128 + wq * 4) = v;
}

// ---------------- forward DFT along w via MFMA: x -> T(B,C,H,16)cplx ----------
__global__ __launch_bounds__(256) void k_dft_w2(const float* __restrict__ x,
        float* __restrict__ T, const unsigned short* __restrict__ efp) {
    __shared__ __align__(16) char Xb[32768];
    int t = threadIdx.x;
    size_t r0 = (size_t)blockIdx.x * 64;     // 64 rows (b,c,h)
    const float4* xg = (const float4*)(x + r0 * 128);
    #pragma unroll
    for (int k = 0; k < 8; ++k) {
        int idx4 = k * 256 + t;
        float4 f = xg[idx4];
        int row = idx4 >> 5;
        int w0 = (idx4 & 31) * 4;
        s4v h4, l4;
        const float* fp = (const float*)&f;
        #pragma unroll
        for (int q = 0; q < 4; ++q) {
            unsigned short hh, ll;
            split_bf16(fp[q], hh, ll);
            h4[q] = (short)hh; l4[q] = (short)ll;
        }
        int byt = row * 256 + ((w0 * 2) ^ ((row & 7) << 4));
        *(s4v*)(Xb + byt) = h4;
        *(s4v*)(Xb + 16384 + byt) = l4;
    }
    __syncthreads();
    int lane = t & 63, wv = t >> 6;
    f4v acc[2];
    acc[0] = (f4v){0.f, 0.f, 0.f, 0.f};
    acc[1] = (f4v){0.f, 0.f, 0.f, 0.f};
    #pragma unroll
    for (int kc = 0; kc < 4; ++kc) {
        int row = wv * 16 + (lane & 15);
        int k0 = kc * 32 + ((lane >> 4) << 3);
        int byt = row * 256 + ((k0 * 2) ^ ((row & 7) << 4));
        s8v ah = *(const s8v*)(Xb + byt);
        s8v al = *(const s8v*)(Xb + 16384 + byt);
        #pragma unroll
        for (int nt = 0; nt < 2; ++nt) {
            const unsigned short* bp = efp + ((kc * 2 + nt) * 64 + lane) * 8;
            s8v bh = *(const s8v*)bp;
            s8v bl = *(const s8v*)(bp + 4096);
            acc[nt] = MFMA16(ah, bh, acc[nt]);
            acc[nt] = MFMA16(ah, bl, acc[nt]);
            acc[nt] = MFMA16(al, bh, acc[nt]);
        }
    }
    #pragma unroll
    for (int nt = 0; nt < 2; ++nt)
        #pragma unroll
        for (int r = 0; r < 4; ++r)
            T[(r0 + wv * 16 + (lane >> 4) * 4 + r) * 32 + nt * 16 + (lane & 15)] = acc[nt][r];
}

// ---------------- forward DFT along h ----------------
__global__ __launch_bounds__(256) void k_dft_h(const float* __restrict__ T,
        float* __restrict__ F, const float* __restrict__ tabH) {
    __shared__ float Ts[4096];
    __shared__ float Eh[8192];
    int t = threadIdx.x, bi = blockIdx.x;
    #pragma unroll
    for (int k = 0; k < 32; ++k) Eh[k * 256 + t] = tabH[k * 256 + t];
    const float* Tp = T + (size_t)bi * 4096;
    #pragma unroll
    for (int k = 0; k < 16; ++k) Ts[k * 256 + t] = Tp[k * 256 + t];
    __syncthreads();
    int kxi = t & 31, g = t >> 5;
    int ky0 = g * 2;
    float ar0 = 0.f, ai0 = 0.f, ar1 = 0.f, ai1 = 0.f;
    for (int h = 0; h < 128; ++h) {
        float er = Eh[h * 64 + kxi * 2], ei = Eh[h * 64 + kxi * 2 + 1];
        float tr0 = Ts[h * 32 + ky0 * 2],     ti0 = Ts[h * 32 + ky0 * 2 + 1];
        float tr1 = Ts[h * 32 + ky0 * 2 + 2], ti1 = Ts[h * 32 + ky0 * 2 + 3];
        ar0 += tr0 * er - ti0 * ei;  ai0 += tr0 * ei + ti0 * er;
        ar1 += tr1 * er - ti1 * ei;  ai1 += tr1 * ei + ti1 * er;
    }
    *(float4*)(F + (size_t)bi * 1024 + (kxi * 16 + ky0) * 2) = make_float4(ar0, ai0, ar1, ai1);
}

// ---------------- per-mode complex C x C mix (b-split, optional i-split) --------
template<int ISPLIT>
__global__ __launch_bounds__(256) void k_modemix(const float* __restrict__ F,
        float* __restrict__ Ga, float* __restrict__ Gb,
        const float* __restrict__ w1r, const float* __restrict__ w1i,
        const float* __restrict__ w2r, const float* __restrict__ w2i) {
    int t = threadIdx.x;
    int m = blockIdx.x * 64 + (t & 63);
    int o = blockIdx.y * 4 + (t >> 6);
    int bz = blockIdx.z;
    int ih = ISPLIT ? (bz & 1) : 0;
    int b0 = (ISPLIT ? (bz >> 1) : bz) * 4;
    const float* wrp = (m < 256) ? w1r : w2r;
    const float* wip = (m < 256) ? w1i : w2i;
    int ms = m & 255;
    float accr[4], acci[4];
    #pragma unroll
    for (int b = 0; b < 4; ++b) { accr[b] = 0.f; acci[b] = 0.f; }
    const int ni = ISPLIT ? 64 : 128;
    const size_t i0 = (size_t)ih * 64;
    const float* wrb = wrp + (i0 * 128 + o) * 256 + ms;
    const float* wib = wip + (i0 * 128 + o) * 256 + ms;
    const float* Fb = F + i0 * 1024 + m * 2 + (size_t)b0 * 131072;
    #pragma unroll 4
    for (int ii = 0; ii < ni; ++ii) {
        float wr = wrb[(size_t)ii * 32768];
        float wi = wib[(size_t)ii * 32768];
        const float* Fp = Fb + (size_t)ii * 1024;
        #pragma unroll
        for (int b = 0; b < 4; ++b) {
            float fr = Fp[b * 131072];
            float fi = Fp[b * 131072 + 1];
            accr[b] += fr * wr - fi * wi;
            acci[b] += fr * wi + fi * wr;
        }
    }
    float* Gp = (ISPLIT && ih) ? Gb : Ga;
    #pragma unroll
    for (int b = 0; b < 4; ++b) {
        float* g = Gp + ((size_t)((b0 + b) * 128 + o) * 512 + m) * 2;
        g[0] = accr[b]; g[1] = acci[b];
    }
}

// ---------------- inverse DFT along h (optionally summing two partial G) ------
template<int ADD>
__global__ __launch_bounds__(256) void k_idft_h(const float* __restrict__ G,
        const float* __restrict__ G2, float* __restrict__ Z,
        const float* __restrict__ tabH) {
    __shared__ float Gs[1024];
    __shared__ float Eh[8192];
    int t = threadIdx.x, bo = blockIdx.x;
    #pragma unroll
    for (int k = 0; k < 32; ++k) Eh[k * 256 + t] = tabH[k * 256 + t];
    const float* Gp = G + (size_t)bo * 1024;
    const float* G2p = G2 + (size_t)bo * 1024;
    #pragma unroll
    for (int k = 0; k < 4; ++k)
        Gs[k * 256 + t] = ADD ? (Gp[k * 256 + t] + G2p[k * 256 + t]) : Gp[k * 256 + t];
    __syncthreads();
    int ky = t & 15, hb = t >> 4;
    float zr[8], zi[8];
    #pragma unroll
    for (int j = 0; j < 8; ++j) { zr[j] = 0.f; zi[j] = 0.f; }
    for (int kxi = 0; kxi < 32; ++kxi) {
        float gr = Gs[(kxi * 16 + ky) * 2], gi = Gs[(kxi * 16 + ky) * 2 + 1];
        #pragma unroll
        for (int j = 0; j < 8; ++j) {
            int h = hb + 16 * j;
            float c = Eh[h * 64 + kxi * 2], s = Eh[h * 64 + kxi * 2 + 1];
            zr[j] += gr * c + gi * s;
            zi[j] += gi * c - gr * s;
        }
    }
    float* Zp = Z + (size_t)bo * 4096;
    #pragma unroll
    for (int j = 0; j < 8; ++j) {
        int h = hb + 16 * j;
        Zp[h * 32 + ky * 2] = zr[j];
        Zp[h * 32 + ky * 2 + 1] = zi[j];
    }
}

// ---------------- fused layer tail: Z -> S (MFMA idft_w) -> MLP + skip, in-place ----
template<int ACT>
__global__ __launch_bounds__(256, 3) void k_layer(
    const float* __restrict__ Zbuf, const float* __restrict__ xin,
    const unsigned short* __restrict__ w1p, const float* __restrict__ b1,
    const unsigned short* __restrict__ w2p, const float* __restrict__ b2,
    const unsigned short* __restrict__ wskp, const float* __restrict__ bsk,
    const unsigned short* __restrict__ ef2, float* __restrict__ xout)
{
    __shared__ __align__(16) char Bb[32768];
    int t = threadIdx.x;
    int b = blockIdx.y;
    int p0 = blockIdx.x * 64;
    int h = p0 >> 7, w0 = p0 & 127;
    int lane = t & 63, wv = t >> 6;

    // ---- P0: S = Z . E2 via MFMA (K=32), pack C-frags into Bb ----
    {
        int q0 = (lane >> 4) << 3;
        s8v zah[2], zal[2];
        #pragma unroll
        for (int ct = 0; ct < 2; ++ct) {
            int c = wv * 32 + ct * 16 + (lane & 15);
            const float* zp = Zbuf + ((size_t)(b * 128 + c) * 128 + h) * 32 + q0;
            float4 z0 = *(const float4*)zp;
            float4 z1 = *(const float4*)(zp + 4);
            float zv[8] = {z0.x, z0.y, z0.z, z0.w, z1.x, z1.y, z1.z, z1.w};
            #pragma unroll
            for (int j = 0; j < 8; ++j) {
                unsigned short hh, ll;
                split_bf16(zv[j], hh, ll);
                zah[ct][j] = (short)hh; zal[ct][j] = (short)ll;
            }
        }
        int wtg0 = w0 >> 4;
        #pragma unroll
        for (int wt = 0; wt < 4; ++wt) {
            const unsigned short* bp = ef2 + ((wtg0 + wt) * 64 + lane) * 8;
            s8v bh = *(const s8v*)bp;
            s8v bl = *(const s8v*)(bp + 4096);
            #pragma unroll
            for (int ct = 0; ct < 2; ++ct) {
                f4v c4 = (f4v){0.f, 0.f, 0.f, 0.f};
                c4 = MFMA16(zah[ct], bh, c4);
                c4 = MFMA16(zah[ct], bl, c4);
                c4 = MFMA16(zal[ct], bh, c4);
                int px = wt * 16 + (lane & 15);
                int c0 = wv * 32 + ct * 16 + ((lane >> 4) << 2);
                s4v h4, l4;
                #pragma unroll
                for (int r = 0; r < 4; ++r) {
                    unsigned short hh, ll;
                    split_bf16(c4[r], hh, ll);
                    h4[r] = (short)hh; l4[r] = (short)ll;
                }
                int byt = px * 256 + ((c0 * 2) ^ ((px & 7) << 4));
                *(s4v*)(Bb + byt) = h4;
                *(s4v*)(Bb + 16384 + byt) = l4;
            }
        }
    }
    __syncthreads();

    f4v acc[2][4];
    #pragma unroll
    for (int oi = 0; oi < 2; ++oi)
        #pragma unroll
        for (int pt = 0; pt < 4; ++pt) acc[oi][pt] = (f4v){0.f, 0.f, 0.f, 0.f};

    // ---- P1: acc = W1 . S ----
    gemm_range<0, 4>(Bb, w1p, lane, wv, acc);
    __syncthreads();                       // all S reads done

    // issue x prefetch half 0 (channels 0..63); lands during Mid-pack + P2
    float xr[16];
    #pragma unroll
    for (int j = 0; j < 16; ++j)
        xr[j] = xin[((size_t)(b * 128 + wv * 16 + j)) * 16384 + p0 + lane];

    // Mid = gelu(acc + b1) -> overwrite Bb
    #pragma unroll
    for (int oi = 0; oi < 2; ++oi) {
        int o0 = wv * 32 + oi * 16 + ((lane >> 4) << 2);
        float bv[4];
        #pragma unroll
        for (int r = 0; r < 4; ++r) bv[r] = b1[o0 + r];
        #pragma unroll
        for (int pt = 0; pt < 4; ++pt) {
            int px = pt * 16 + (lane & 15);
            s4v h4, l4;
            #pragma unroll
            for (int r = 0; r < 4; ++r) {
                unsigned short hh, ll;
                split_bf16(gelu_f(acc[oi][pt][r] + bv[r]), hh, ll);
                h4[r] = (short)hh; l4[r] = (short)ll;
            }
            int byt = px * 256 + ((o0 * 2) ^ ((px & 7) << 4));
            *(s4v*)(Bb + byt) = h4;
            *(s4v*)(Bb + 16384 + byt) = l4;
            acc[oi][pt] = (f4v){0.f, 0.f, 0.f, 0.f};
        }
    }
    __syncthreads();

    // ---- P2: acc = W2 . Mid ----
    gemm_range<0, 4>(Bb, w2p, lane, wv, acc);
    __syncthreads();                       // all Mid reads done

    // ---- P3: skip GEMM in two K-halves, packing one half while computing the other ----
    pack_write8(Bb, lane, wv * 16, xr);
    pack_write8(Bb, lane, wv * 16 + 8, xr + 8);
    #pragma unroll
    for (int j = 0; j < 16; ++j)           // half 1 (channels 64..127)
        xr[j] = xin[((size_t)(b * 128 + 64 + wv * 16 + j)) * 16384 + p0 + lane];
    __syncthreads();
    gemm_range<0, 2>(Bb, wskp, lane, wv, acc);
    pack_write8(Bb, lane, 64 + wv * 16, xr);
    pack_write8(Bb, lane, 64 + wv * 16 + 8, xr + 8);
    __syncthreads();
    gemm_range<2, 2>(Bb, wskp, lane, wv, acc);

    // ---- epilogue: in-place write ----
    #pragma unroll
    for (int oi = 0; oi < 2; ++oi) {
        int o0 = wv * 32 + oi * 16 + ((lane >> 4) << 2);
        float bv[4];
        #pragma unroll
        for (int r = 0; r < 4; ++r) bv[r] = b2[o0 + r] + bsk[o0 + r];
        #pragma unroll
        for (int pt = 0; pt < 4; ++pt) {
            int px = pt * 16 + (lane & 15);
            #pragma unroll
            for (int r = 0; r < 4; ++r) {
                float xv = acc[oi][pt][r] + bv[r];
                if (ACT) xv = gelu_f(xv);
                xout[((size_t)(b * 128 + o0 + r)) * 16384 + p0 + px] = xv;
            }
        }
    }
}

// ---------------- fused projection ----------------
__global__ __launch_bounds__(256) void k_proj(const float* __restrict__ xin,
        const unsigned short* __restrict__ wap, const float* __restrict__ ba,
        const float* __restrict__ wb, const float* __restrict__ bb,
        float* __restrict__ outp) {
    __shared__ __align__(16) char Bb[32768];
    __shared__ float Red[256];
    int t = threadIdx.x;
    int b = blockIdx.y;
    int p0 = blockIdx.x * 64;
    int lane = t & 63, wv = t >> 6;

    float xr[16];
    #pragma unroll
    for (int j = 0; j < 16; ++j)
        xr[j] = xin[((size_t)(b * 128 + wv * 16 + j)) * 16384 + p0 + lane];
    pack_write8(Bb, lane, wv * 16, xr);
    pack_write8(Bb, lane, wv * 16 + 8, xr + 8);
    #pragma unroll
    for (int j = 0; j < 16; ++j)
        xr[j] = xin[((size_t)(b * 128 + 64 + wv * 16 + j)) * 16384 + p0 + lane];
    pack_write8(Bb, lane, 64 + wv * 16, xr);
    pack_write8(Bb, lane, 64 + wv * 16 + 8, xr + 8);
    __syncthreads();

    f4v acc[2][4];
    #pragma unroll
    for (int oi = 0; oi < 2; ++oi)
        #pragma unroll
        for (int pt = 0; pt < 4; ++pt) acc[oi][pt] = (f4v){0.f, 0.f, 0.f, 0.f};
    gemm_range<0, 4>(Bb, wap, lane, wv, acc);

    float pxsum[4] = {0.f, 0.f, 0.f, 0.f};
    #pragma unroll
    for (int oi = 0; oi < 2; ++oi) {
        int o0 = wv * 32 + oi * 16 + ((lane >> 4) << 2);
        #pragma unroll
        for (int r = 0; r < 4; ++r) {
            float bav = ba[o0 + r];
            float wbv = wb[o0 + r];
            #pragma unroll
            for (int pt = 0; pt < 4; ++pt)
                pxsum[pt] += wbv * gelu_f(acc[oi][pt][r] + bav);
        }
    }
    #pragma unroll
    for (int pt = 0; pt < 4; ++pt) {
        float v = pxsum[pt];
        v += __shfl_xor(v, 16);
        v += __shfl_xor(v, 32);
        if (lane < 16) Red[wv * 64 + pt * 16 + lane] = v;
    }
    __syncthreads();
    if (t < 64)
        outp[(size_t)b * 16384 + p0 + t] = bb[0] + Red[t] + Red[64 + t] + Red[128 + t] + Red[192 + t];
}

extern "C" void kernel_launch(void* const* d_in, const int* in_sizes, int n_in,
                              void* d_out, int out_size, void* d_ws, size_t ws_size,
                              hipStream_t stream) {
    (void)in_sizes; (void)n_in; (void)out_size;
    const float* x     = (const float*)d_in[0];
    const float* w1r   = (const float*)d_in[1];
    const float* w1i   = (const float*)d_in[2];
    const float* w2r   = (const float*)d_in[3];
    const float* w2i   = (const float*)d_in[4];
    const float* mlp1w = (const float*)d_in[5];
    const float* mlp1b = (const float*)d_in[6];
    const float* mlp2w = (const float*)d_in[7];
    const float* mlp2b = (const float*)d_in[8];
    const float* wsw   = (const float*)d_in[9];
    const float* wsb   = (const float*)d_in[10];
    const float* fc0w  = (const float*)d_in[11];
    const float* fc0b  = (const float*)d_in[12];
    const float* fc1aw = (const float*)d_in[13];
    const float* fc1ab = (const float*)d_in[14];
    const float* fc1bw = (const float*)d_in[15];
    const float* fc1bb = (const float*)d_in[16];
    float* out = (float*)d_out;

    float* ws   = (float*)d_ws;
    float* xA   = ws;                        // 33,554,432
    float* T    = ws + 33554432;             //  8,388,608
    float* F    = T + 8388608;               //  2,097,152
    float* Ga   = F + 2097152;               //  2,097,152
    float* tabH = Ga + 2097152;              //  8192
    unsigned short* wpack = (unsigned short*)(tabH + 8192);  // 13*32768 ushort
    unsigned short* efp   = wpack + 13 * 32768;              // 8192 ushort
    unsigned short* ef2   = efp + 8192;                      // 8192 ushort
    float* Gb   = (float*)(ef2 + 8192);      //  2,097,152 (optional)
    size_t need_split = ((char*)(Gb + 2097152)) - (char*)d_ws;
    bool isplit = ws_size >= need_split;

    k_init_tables<<<32, 256, 0, stream>>>(tabH);
    k_pack_w<<<832, 256, 0, stream>>>(mlp1w, mlp2w, wsw, fc1aw, wpack);
    k_pack_ef<<<16, 256, 0, stream>>>(efp, ef2);
    k_lift<<<32768, 256, 0, stream>>>(x, fc0w, fc0b, xA);

    for (int l = 0; l < 4; ++l) {
        k_dft_w2<<<4096, 256, 0, stream>>>(xA, T, efp);
        k_dft_h<<<2048, 256, 0, stream>>>(T, F, tabH);
        const float* l1r = w1r + (size_t)l * 4194304;
        const float* l1i = w1i + (size_t)l * 4194304;
        const float* l2r = w2r + (size_t)l * 4194304;
        const float* l2i = w2i + (size_t)l * 4194304;
        if (isplit) {
            k_modemix<1><<<dim3(8, 32, 8), 256, 0, stream>>>(F, Ga, Gb, l1r, l1i, l2r, l2i);
            k_idft_h<1><<<2048, 256, 0, stream>>>(Ga, Gb, T, tabH);
        } else {
            k_modemix<0><<<dim3(8, 32, 4), 256, 0, stream>>>(F, Ga, Ga, l1r, l1i, l2r, l2i);
            k_idft_h<0><<<2048, 256, 0, stream>>>(Ga, Ga, T, tabH);
        }
        const unsigned short* w1p  = wpack + (size_t)l * 32768;
        const unsigned short* w2p  = wpack + (size_t)(4 + l) * 32768;
        const unsigned short* wskp = wpack + (size_t)(8 + l) * 32768;
        if (l < 3)
            k_layer<1><<<dim3(256, 16), 256, 0, stream>>>(T, xA,
                w1p, mlp1b + l * 128, w2p, mlp2b + l * 128,
                wskp, wsb + l * 128, ef2, xA);
        else
            k_layer<0><<<dim3(256, 16), 256, 0, stream>>>(T, xA,
                w1p, mlp1b + l * 128, w2p, mlp2b + l * 128,
                wskp, wsb + l * 128, ef2, xA);
    }
    k_proj<<<dim3(256, 16), 256, 0, stream>>>(xA, wpack + (size_t)12 * 32768,
        fc1ab, fc1bw, fc1bb, out);
}

// Round 7
// 1160.212 us; speedup vs baseline: 3.6460x; 1.1131x over previous
//
#include <hip/hip_runtime.h>
#include <math.h>

#define PI_F 3.14159265358979323846f

typedef __attribute__((ext_vector_type(8))) short s8v;
typedef __attribute__((ext_vector_type(4))) short s4v;
typedef __attribute__((ext_vector_type(4))) float f4v;

#define MFMA16(a, b, c) __builtin_amdgcn_mfma_f32_16x16x32_bf16(a, b, c, 0, 0, 0)

// fast erf, A&S 7.1.26, |err| <= 1.5e-7
__device__ __forceinline__ float erf_f(float x) {
    float a = fabsf(x);
    float t = 1.0f / fmaf(0.3275911f, a, 1.0f);
    float p = t * fmaf(t, fmaf(t, fmaf(t, fmaf(t, 1.061405429f, -1.453152027f),
                1.421413741f), -0.284496736f), 0.254829592f);
    float r = 1.0f - p * __expf(-a * a);
    return copysignf(r, x);
}
__device__ __forceinline__ float gelu_f(float x) {
    return 0.5f * x * (1.0f + erf_f(x * 0.70710678118654752440f));
}

__device__ __forceinline__ unsigned bf16_rn_bits(float x) {
    unsigned u = __builtin_bit_cast(unsigned, x);
    return (u + 0x7FFFu + ((u >> 16) & 1u)) & 0xFFFF0000u;
}
// truncate-hi split: hi = trunc(x), lo = round(x - hi). Total err ~2^-17 rel
// (lo corrects hi exactly; lo itself rounded).
__device__ __forceinline__ void split_bf16(float x, unsigned short& h, unsigned short& l) {
    unsigned u = __builtin_bit_cast(unsigned, x);
    h = (unsigned short)(u >> 16);
    float hf = __builtin_bit_cast(float, u & 0xFFFF0000u);
    l = (unsigned short)(bf16_rn_bits(x - hf) >> 16);
}

// pack 8 fp32 (consecutive k, k0 mult of 8) into swizzled hi/lo LDS B-buffer
// layout: [px 0..63][k 0..127] bf16, hi @0, lo @16384; byte ^= ((px&15)<<4)
__device__ __forceinline__ void pack_write8(char* Bb, int px, int k0, const float* v) {
    s8v hv, lv;
    #pragma unroll
    for (int j = 0; j < 8; ++j) {
        unsigned short h, l;
        split_bf16(v[j], h, l);
        hv[j] = (short)h; lv[j] = (short)l;
    }
    int byt = px * 256 + ((k0 * 2) ^ ((px & 15) << 4));
    *(s8v*)(Bb + byt) = hv;
    *(s8v*)(Bb + 16384 + byt) = lv;
}

// 128(o) x 64(px) x 32*KCN(k) GEMM accumulate via split-bf16 MFMA, kc in [KC0,KC0+KCN)
template<int KC0, int KCN>
__device__ __forceinline__ void gemm_range(const char* Bb, const unsigned short* wp,
                                           int lane, int wv, f4v acc[2][4]) {
    #pragma unroll
    for (int kc = KC0; kc < KC0 + KCN; ++kc) {
        s8v bh[4], bl[4];
        int k0 = kc * 32 + ((lane >> 4) << 3);
        #pragma unroll
        for (int pt = 0; pt < 4; ++pt) {
            int px = pt * 16 + (lane & 15);
            int byt = px * 256 + ((k0 * 2) ^ ((px & 15) << 4));
            bh[pt] = *(const s8v*)(Bb + byt);
            bl[pt] = *(const s8v*)(Bb + 16384 + byt);
        }
        #pragma unroll
        for (int oi = 0; oi < 2; ++oi) {
            const unsigned short* ap = wp + (wv * 2 + oi) * 2048 + kc * 512 + lane * 8;
            s8v ah = *(const s8v*)ap;
            s8v al = *(const s8v*)(ap + 16384);
            #pragma unroll
            for (int pt = 0; pt < 4; ++pt) {
                acc[oi][pt] = MFMA16(ah, bh[pt], acc[oi][pt]);
                acc[oi][pt] = MFMA16(ah, bl[pt], acc[oi][pt]);
                acc[oi][pt] = MFMA16(al, bh[pt], acc[oi][pt]);
            }
        }
    }
}

// ---------------- weight pre-split+pack: 13 fp32 128x128 mats ----------------
__global__ __launch_bounds__(256) void k_pack_w(const float* __restrict__ mlp1w,
        const float* __restrict__ mlp2w, const float* __restrict__ wsw,
        const float* __restrict__ fc1aw, unsigned short* __restrict__ wpack) {
    int idx = blockIdx.x * 256 + threadIdx.x;
    if (idx >= 212992) return;           // 13 * 16384
    int mat = idx >> 14, e = idx & 16383;
    const float* src = mat < 4  ? mlp1w + mat * 16384 + e
                     : mat < 8  ? mlp2w + (mat - 4) * 16384 + e
                     : mat < 12 ? wsw + (mat - 8) * 16384 + e
                                : fc1aw + e;
    float x = *src;
    unsigned short h, l;
    split_bf16(x, h, l);
    int o = e >> 7, i = e & 127;
    int pos = (o >> 4) * 2048 + (i >> 5) * 512 + (((i >> 3) & 3) * 16 + (o & 15)) * 8 + (i & 7);
    wpack[(size_t)mat * 32768 + pos] = h;
    wpack[(size_t)mat * 32768 + 16384 + pos] = l;
}

// ---------------- twiddle fragment tables ----------------
// efp: forward-w DFT B-frags [kc4][nt2][lane64][j8], hi @0, lo @+4096 (ushort)
// ef2: inverse-w DFT B-frags [wt8][lane64][j8], hi @0, lo @+4096, incl irfft scale
// ef3: forward-h DFT doubled-real B-frags [ct4][kt8][lane64][j8], hi @0, lo @+16384
//      B[k=2h+cb][col=2kxi+cp]: (cb,cp)=(0,0):Er (1,0):-Ei (0,1):Ei (1,1):Er
//      with Er=cos(th), Ei=-sin(th), th = 2pi*((f(kxi)*h) mod 128)/128
__global__ void k_pack_ef(unsigned short* __restrict__ efp,
                          unsigned short* __restrict__ ef2,
                          unsigned short* __restrict__ ef3) {
    int t = blockIdx.x * 256 + threadIdx.x;
    if (t < 4096) {
        int j = t & 7, lane = (t >> 3) & 63, nt = (t >> 9) & 1, kc = t >> 10;
        int w = kc * 32 + ((lane >> 4) << 3) + j;
        int q = nt * 16 + (lane & 15);
        int ky = q >> 1, c = q & 1;
        int m = (ky * w) & 127;
        float th = (2.0f * PI_F / 128.0f) * (float)m;
        float v = c ? -sinf(th) : cosf(th);
        unsigned short h, l;
        split_bf16(v, h, l);
        efp[t] = h;
        efp[4096 + t] = l;
    }
    if (t < 4096) {
        int j = t & 7, lane = (t >> 3) & 63, wt = t >> 9;
        int w = wt * 16 + (lane & 15);
        int q = ((lane >> 4) << 3) + j;
        int ky = q >> 1, c = q & 1;
        float g = (ky == 0 ? 1.0f : 2.0f) * (1.0f / 16384.0f);
        int m = (ky * w) & 127;
        float th = (2.0f * PI_F / 128.0f) * (float)m;
        float v = (c ? -sinf(th) : cosf(th)) * g;
        unsigned short h, l;
        split_bf16(v, h, l);
        ef2[t] = h;
        ef2[4096 + t] = l;
    }
    if (t < 16384) {
        int j = t & 7, lane = (t >> 3) & 63, kt = (t >> 9) & 7, ct = t >> 12;
        int k = kt * 32 + ((lane >> 4) << 3) + j;
        int col = ct * 16 + (lane & 15);
        int h = k >> 1, cb = k & 1;
        int kxi = col >> 1, cp = col & 1;
        int f = kxi < 16 ? kxi : kxi - 32;
        int m = ((f * h) % 128 + 128) & 127;
        float th = (2.0f * PI_F / 128.0f) * (float)m;
        float Er = cosf(th), Ei = -sinf(th);
        float v = (cb == 0) ? (cp == 0 ? Er : Ei) : (cp == 0 ? -Ei : Er);
        unsigned short hh, ll;
        split_bf16(v, hh, ll);
        ef3[t] = hh;
        ef3[16384 + t] = ll;
    }
}

// ---------------- tabH for inverse h-DFT ----------------
__global__ void k_init_tables(float* __restrict__ tabH) {
    int idx = blockIdx.x * 256 + threadIdx.x;
    if (idx < 8192) {
        int c = idx & 1, kxi = (idx >> 1) & 31, h = idx >> 6;
        int f = kxi < 16 ? kxi : kxi - 32;
        int m = ((f * h) % 128 + 128) & 127;
        float th = (2.0f * PI_F / 128.0f) * (float)m;
        tabH[idx] = c ? -sinf(th) : cosf(th);
    }
}

// ---------------- lifting (4 px / thread, float4) ----------------
__global__ __launch_bounds__(256) void k_lift(const float* __restrict__ xin,
        const float* __restrict__ w0, const float* __restrict__ b0,
        float* __restrict__ xout) {
    int idx = blockIdx.x * 256 + threadIdx.x;     // 8,388,608 quads
    int wq = idx & 31, h = (idx >> 5) & 127, c = (idx >> 12) & 127, b = idx >> 19;
    const float4* xp = (const float4*)(xin + ((size_t)(b * 128 + h) * 128 + wq * 4) * 2);
    float4 p01 = xp[0], p23 = xp[1];
    float wa = w0[c], wbv = w0[128 + c], wg = w0[256 + c], wd = w0[384 + c];
    float base = (float)h * (1.0f / 127.0f) * wg + b0[c];
    float ws = (1.0f / 127.0f) * wd;
    float4 v;
    v.x = p01.x * wa + p01.y * wbv + (float)(wq * 4 + 0) * ws + base;
    v.y = p01.z * wa + p01.w * wbv + (float)(wq * 4 + 1) * ws + base;
    v.z = p23.x * wa + p23.y * wbv + (float)(wq * 4 + 2) * ws + base;
    v.w = p23.z * wa + p23.w * wbv + (float)(wq * 4 + 3) * ws + base;
    *(float4*)(xout + ((size_t)(b * 128 + c) * 128 + h) * 128 + wq * 4) = v;
}

// ---------------- fused forward transform: x(b,c) -> F[bi][kxi*16+ky]cplx ------
// phase 1: w-DFT via MFMA (2 halves of 64 h-rows), T scattered to Tq LDS
//          Tq layout: [ky 16][k=2h+c 256] bf16, hi @0, lo @+8192, swz ((ky&15)<<4)
// phase 2: h-DFT via doubled-real MFMA: A=Tq rows ky, B=ef3 cols 2kxi+cp
__global__ __launch_bounds__(256) void k_fwd(const float* __restrict__ x,
        float* __restrict__ F, const unsigned short* __restrict__ efp,
        const unsigned short* __restrict__ ef3) {
    __shared__ __align__(16) char Xb[32768];
    __shared__ __align__(16) char Tq[16384];
    int t = threadIdx.x;
    int bi = blockIdx.x;
    int lane = t & 63, wv = t >> 6;
    const float4* xg = (const float4*)(x + (size_t)bi * 16384);

    for (int half = 0; half < 2; ++half) {
        __syncthreads();                 // Xb reuse guard (no-op cost at half 0)
        #pragma unroll
        for (int k = 0; k < 8; ++k) {
            int idx4 = k * 256 + t;
            float4 f = xg[half * 2048 + idx4];
            int row = idx4 >> 5;
            int w0 = (idx4 & 31) * 4;
            s4v h4, l4;
            const float* fp = (const float*)&f;
            #pragma unroll
            for (int q = 0; q < 4; ++q) {
                unsigned short hh, ll;
                split_bf16(fp[q], hh, ll);
                h4[q] = (short)hh; l4[q] = (short)ll;
            }
            int byt = row * 256 + ((w0 * 2) ^ ((row & 15) << 4));
            *(s4v*)(Xb + byt) = h4;
            *(s4v*)(Xb + 16384 + byt) = l4;
        }
        __syncthreads();
        f4v acc[2];
        acc[0] = (f4v){0.f, 0.f, 0.f, 0.f};
        acc[1] = (f4v){0.f, 0.f, 0.f, 0.f};
        #pragma unroll
        for (int kc = 0; kc < 4; ++kc) {
            int row = wv * 16 + (lane & 15);
            int k0 = kc * 32 + ((lane >> 4) << 3);
            int byt = row * 256 + ((k0 * 2) ^ ((row & 15) << 4));
            s8v ah = *(const s8v*)(Xb + byt);
            s8v al = *(const s8v*)(Xb + 16384 + byt);
            #pragma unroll
            for (int nt = 0; nt < 2; ++nt) {
                const unsigned short* bp = efp + ((kc * 2 + nt) * 64 + lane) * 8;
                s8v bh = *(const s8v*)bp;
                s8v bl = *(const s8v*)(bp + 4096);
                acc[nt] = MFMA16(ah, bh, acc[nt]);
                acc[nt] = MFMA16(ah, bl, acc[nt]);
                acc[nt] = MFMA16(al, bh, acc[nt]);
            }
        }
        // scatter T (split-bf16) into Tq: T[h][q] -> Tq[ky=q>>1][k=2h+(q&1)]
        #pragma unroll
        for (int nt = 0; nt < 2; ++nt) {
            int q = nt * 16 + (lane & 15);
            int ky = q >> 1, c = q & 1;
            #pragma unroll
            for (int r = 0; r < 4; ++r) {
                int h = half * 64 + wv * 16 + ((lane >> 4) << 2) + r;
                unsigned short hh, ll;
                split_bf16(acc[nt][r], hh, ll);
                int byt = ky * 512 + ((4 * h + 2 * c) ^ ((ky & 15) << 4));
                *(unsigned short*)(Tq + byt) = hh;
                *(unsigned short*)(Tq + 8192 + byt) = ll;
            }
        }
    }
    __syncthreads();
    // h-DFT: wave wv owns col-tile ct=wv (cols 2kxi+cp), K=256
    f4v fa = (f4v){0.f, 0.f, 0.f, 0.f};
    #pragma unroll
    for (int kt = 0; kt < 8; ++kt) {
        int ky = lane & 15;
        int byt = ky * 512 + ((kt * 64 + ((lane >> 4) << 4)) ^ ((ky & 15) << 4));
        s8v ah = *(const s8v*)(Tq + byt);
        s8v al = *(const s8v*)(Tq + 8192 + byt);
        const unsigned short* bp = ef3 + ((wv * 8 + kt) * 64 + lane) * 8;
        s8v bh = *(const s8v*)bp;
        s8v bl = *(const s8v*)(bp + 16384);
        fa = MFMA16(ah, bh, fa);
        fa = MFMA16(ah, bl, fa);
        fa = MFMA16(al, bh, fa);
    }
    int col = wv * 16 + (lane & 15);
    int kxi = col >> 1, cp = col & 1;
    float* Fb = F + (size_t)bi * 1024 + kxi * 32 + cp;
    #pragma unroll
    for (int r = 0; r < 4; ++r) {
        int ky = ((lane >> 4) << 2) + r;
        Fb[ky * 2] = fa[r];
    }
}

// ---------------- per-mode complex C x C mix (b-split, optional i-split) --------
template<int ISPLIT>
__global__ __launch_bounds__(256) void k_modemix(const float* __restrict__ F,
        float* __restrict__ Ga, float* __restrict__ Gb,
        const float* __restrict__ w1r, const float* __restrict__ w1i,
        const float* __restrict__ w2r, const float* __restrict__ w2i) {
    int t = threadIdx.x;
    int m = blockIdx.x * 64 + (t & 63);
    int o = blockIdx.y * 4 + (t >> 6);
    int bz = blockIdx.z;
    int ih = ISPLIT ? (bz & 1) : 0;
    int b0 = (ISPLIT ? (bz >> 1) : bz) * 4;
    const float* wrp = (m < 256) ? w1r : w2r;
    const float* wip = (m < 256) ? w1i : w2i;
    int ms = m & 255;
    float accr[4], acci[4];
    #pragma unroll
    for (int b = 0; b < 4; ++b) { accr[b] = 0.f; acci[b] = 0.f; }
    const int ni = ISPLIT ? 64 : 128;
    const size_t i0 = (size_t)ih * 64;
    const float* wrb = wrp + (i0 * 128 + o) * 256 + ms;
    const float* wib = wip + (i0 * 128 + o) * 256 + ms;
    const float* Fb = F + i0 * 1024 + m * 2 + (size_t)b0 * 131072;
    #pragma unroll 4
    for (int ii = 0; ii < ni; ++ii) {
        float wr = wrb[(size_t)ii * 32768];
        float wi = wib[(size_t)ii * 32768];
        const float* Fp = Fb + (size_t)ii * 1024;
        #pragma unroll
        for (int b = 0; b < 4; ++b) {
            float fr = Fp[b * 131072];
            float fi = Fp[b * 131072 + 1];
            accr[b] += fr * wr - fi * wi;
            acci[b] += fr * wi + fi * wr;
        }
    }
    float* Gp = (ISPLIT && ih) ? Gb : Ga;
    #pragma unroll
    for (int b = 0; b < 4; ++b) {
        float* g = Gp + ((size_t)((b0 + b) * 128 + o) * 512 + m) * 2;
        g[0] = accr[b]; g[1] = acci[b];
    }
}

// ---------------- inverse DFT along h (optionally summing two partial G) ------
template<int ADD>
__global__ __launch_bounds__(256) void k_idft_h(const float* __restrict__ G,
        const float* __restrict__ G2, float* __restrict__ Z,
        const float* __restrict__ tabH) {
    __shared__ float Gs[1024];
    __shared__ float Eh[8192];
    int t = threadIdx.x, bo = blockIdx.x;
    #pragma unroll
    for (int k = 0; k < 32; ++k) Eh[k * 256 + t] = tabH[k * 256 + t];
    const float* Gp = G + (size_t)bo * 1024;
    const float* G2p = G2 + (size_t)bo * 1024;
    #pragma unroll
    for (int k = 0; k < 4; ++k)
        Gs[k * 256 + t] = ADD ? (Gp[k * 256 + t] + G2p[k * 256 + t]) : Gp[k * 256 + t];
    __syncthreads();
    int ky = t & 15, hb = t >> 4;
    float zr[8], zi[8];
    #pragma unroll
    for (int j = 0; j < 8; ++j) { zr[j] = 0.f; zi[j] = 0.f; }
    for (int kxi = 0; kxi < 32; ++kxi) {
        float gr = Gs[(kxi * 16 + ky) * 2], gi = Gs[(kxi * 16 + ky) * 2 + 1];
        #pragma unroll
        for (int j = 0; j < 8; ++j) {
            int h = hb + 16 * j;
            float c = Eh[h * 64 + kxi * 2], s = Eh[h * 64 + kxi * 2 + 1];
            zr[j] += gr * c + gi * s;
            zi[j] += gi * c - gr * s;
        }
    }
    float* Zp = Z + (size_t)bo * 4096;
    #pragma unroll
    for (int j = 0; j < 8; ++j) {
        int h = hb + 16 * j;
        Zp[h * 32 + ky * 2] = zr[j];
        Zp[h * 32 + ky * 2 + 1] = zi[j];
    }
}

// ---------------- fused layer tail: Z -> S (MFMA idft_w) -> MLP + skip, in-place ----
template<int ACT>
__global__ __launch_bounds__(256, 3) void k_layer(
    const float* __restrict__ Zbuf, const float* __restrict__ xin,
    const unsigned short* __restrict__ w1p, const float* __restrict__ b1,
    const unsigned short* __restrict__ w2p, const float* __restrict__ b2,
    const unsigned short* __restrict__ wskp, const float* __restrict__ bsk,
    const unsigned short* __restrict__ ef2, float* __restrict__ xout)
{
    __shared__ __align__(16) char Bb[32768];
    int t = threadIdx.x;
    int b = blockIdx.y;
    int p0 = blockIdx.x * 64;
    int h = p0 >> 7, w0 = p0 & 127;
    int lane = t & 63, wv = t >> 6;

    // ---- P0: S = Z . E2 via MFMA (K=32), pack C-frags into Bb ----
    {
        int q0 = (lane >> 4) << 3;
        s8v zah[2], zal[2];
        #pragma unroll
        for (int ct = 0; ct < 2; ++ct) {
            int c = wv * 32 + ct * 16 + (lane & 15);
            const float* zp = Zbuf + ((size_t)(b * 128 + c) * 128 + h) * 32 + q0;
            float4 z0 = *(const float4*)zp;
            float4 z1 = *(const float4*)(zp + 4);
            float zv[8] = {z0.x, z0.y, z0.z, z0.w, z1.x, z1.y, z1.z, z1.w};
            #pragma unroll
            for (int j = 0; j < 8; ++j) {
                unsigned short hh, ll;
                split_bf16(zv[j], hh, ll);
                zah[ct][j] = (short)hh; zal[ct][j] = (short)ll;
            }
        }
        int wtg0 = w0 >> 4;
        #pragma unroll
        for (int wt = 0; wt < 4; ++wt) {
            const unsigned short* bp = ef2 + ((wtg0 + wt) * 64 + lane) * 8;
            s8v bh = *(const s8v*)bp;
            s8v bl = *(const s8v*)(bp + 4096);
            #pragma unroll
            for (int ct = 0; ct < 2; ++ct) {
                f4v c4 = (f4v){0.f, 0.f, 0.f, 0.f};
                c4 = MFMA16(zah[ct], bh, c4);
                c4 = MFMA16(zah[ct], bl, c4);
                c4 = MFMA16(zal[ct], bh, c4);
                int px = wt * 16 + (lane & 15);
                int c0 = wv * 32 + ct * 16 + ((lane >> 4) << 2);
                s4v h4, l4;
                #pragma unroll
                for (int r = 0; r < 4; ++r) {
                    unsigned short hh, ll;
                    split_bf16(c4[r], hh, ll);
                    h4[r] = (short)hh; l4[r] = (short)ll;
                }
                int byt = px * 256 + ((c0 * 2) ^ ((px & 15) << 4));
                *(s4v*)(Bb + byt) = h4;
                *(s4v*)(Bb + 16384 + byt) = l4;
            }
        }
    }
    __syncthreads();

    f4v acc[2][4];
    #pragma unroll
    for (int oi = 0; oi < 2; ++oi)
        #pragma unroll
        for (int pt = 0; pt < 4; ++pt) acc[oi][pt] = (f4v){0.f, 0.f, 0.f, 0.f};

    // ---- P1: acc = W1 . S ----
    gemm_range<0, 4>(Bb, w1p, lane, wv, acc);
    __syncthreads();                       // all S reads done

    // issue x prefetch half 0 (channels 0..63); lands during Mid-pack + P2
    float xr[16];
    #pragma unroll
    for (int j = 0; j < 16; ++j)
        xr[j] = xin[((size_t)(b * 128 + wv * 16 + j)) * 16384 + p0 + lane];

    // Mid = gelu(acc + b1) -> overwrite Bb
    #pragma unroll
    for (int oi = 0; oi < 2; ++oi) {
        int o0 = wv * 32 + oi * 16 + ((lane >> 4) << 2);
        float bv[4];
        #pragma unroll
        for (int r = 0; r < 4; ++r) bv[r] = b1[o0 + r];
        #pragma unroll
        for (int pt = 0; pt < 4; ++pt) {
            int px = pt * 16 + (lane & 15);
            s4v h4, l4;
            #pragma unroll
            for (int r = 0; r < 4; ++r) {
                unsigned short hh, ll;
                split_bf16(gelu_f(acc[oi][pt][r] + bv[r]), hh, ll);
                h4[r] = (short)hh; l4[r] = (short)ll;
            }
            int byt = px * 256 + ((o0 * 2) ^ ((px & 15) << 4));
            *(s4v*)(Bb + byt) = h4;
            *(s4v*)(Bb + 16384 + byt) = l4;
            acc[oi][pt] = (f4v){0.f, 0.f, 0.f, 0.f};
        }
    }
    __syncthreads();

    // ---- P2: acc = W2 . Mid ----
    gemm_range<0, 4>(Bb, w2p, lane, wv, acc);
    __syncthreads();                       // all Mid reads done

    // ---- P3: skip GEMM in two K-halves, packing one half while computing the other ----
    pack_write8(Bb, lane, wv * 16, xr);
    pack_write8(Bb, lane, wv * 16 + 8, xr + 8);
    #pragma unroll
    for (int j = 0; j < 16; ++j)           // half 1 (channels 64..127)
        xr[j] = xin[((size_t)(b * 128 + 64 + wv * 16 + j)) * 16384 + p0 + lane];
    __syncthreads();
    gemm_range<0, 2>(Bb, wskp, lane, wv, acc);
    pack_write8(Bb, lane, 64 + wv * 16, xr);
    pack_write8(Bb, lane, 64 + wv * 16 + 8, xr + 8);
    __syncthreads();
    gemm_range<2, 2>(Bb, wskp, lane, wv, acc);

    // ---- epilogue: in-place write ----
    #pragma unroll
    for (int oi = 0; oi < 2; ++oi) {
        int o0 = wv * 32 + oi * 16 + ((lane >> 4) << 2);
        float bv[4];
        #pragma unroll
        for (int r = 0; r < 4; ++r) bv[r] = b2[o0 + r] + bsk[o0 + r];
        #pragma unroll
        for (int pt = 0; pt < 4; ++pt) {
            int px = pt * 16 + (lane & 15);
            #pragma unroll
            for (int r = 0; r < 4; ++r) {
                float xv = acc[oi][pt][r] + bv[r];
                if (ACT) xv = gelu_f(xv);
                xout[((size_t)(b * 128 + o0 + r)) * 16384 + p0 + px] = xv;
            }
        }
    }
}

// ---------------- fused projection ----------------
__global__ __launch_bounds__(256) void k_proj(const float* __restrict__ xin,
        const unsigned short* __restrict__ wap, const float* __restrict__ ba,
        const float* __restrict__ wb, const float* __restrict__ bb,
        float* __restrict__ outp) {
    __shared__ __align__(16) char Bb[32768];
    __shared__ float Red[256];
    int t = threadIdx.x;
    int b = blockIdx.y;
    int p0 = blockIdx.x * 64;
    int lane = t & 63, wv = t >> 6;

    float xr[16];
    #pragma unroll
    for (int j = 0; j < 16; ++j)
        xr[j] = xin[((size_t)(b * 128 + wv * 16 + j)) * 16384 + p0 + lane];
    pack_write8(Bb, lane, wv * 16, xr);
    pack_write8(Bb, lane, wv * 16 + 8, xr + 8);
    #pragma unroll
    for (int j = 0; j < 16; ++j)
        xr[j] = xin[((size_t)(b * 128 + 64 + wv * 16 + j)) * 16384 + p0 + lane];
    pack_write8(Bb, lane, 64 + wv * 16, xr);
    pack_write8(Bb, lane, 64 + wv * 16 + 8, xr + 8);
    __syncthreads();

    f4v acc[2][4];
    #pragma unroll
    for (int oi = 0; oi < 2; ++oi)
        #pragma unroll
        for (int pt = 0; pt < 4; ++pt) acc[oi][pt] = (f4v){0.f, 0.f, 0.f, 0.f};
    gemm_range<0, 4>(Bb, wap, lane, wv, acc);

    float pxsum[4] = {0.f, 0.f, 0.f, 0.f};
    #pragma unroll
    for (int oi = 0; oi < 2; ++oi) {
        int o0 = wv * 32 + oi * 16 + ((lane >> 4) << 2);
        #pragma unroll
        for (int r = 0; r < 4; ++r) {
            float bav = ba[o0 + r];
            float wbv = wb[o0 + r];
            #pragma unroll
            for (int pt = 0; pt < 4; ++pt)
                pxsum[pt] += wbv * gelu_f(acc[oi][pt][r] + bav);
        }
    }
    #pragma unroll
    for (int pt = 0; pt < 4; ++pt) {
        float v = pxsum[pt];
        v += __shfl_xor(v, 16);
        v += __shfl_xor(v, 32);
        if (lane < 16) Red[wv * 64 + pt * 16 + lane] = v;
    }
    __syncthreads();
    if (t < 64)
        outp[(size_t)b * 16384 + p0 + t] = bb[0] + Red[t] + Red[64 + t] + Red[128 + t] + Red[192 + t];
}

extern "C" void kernel_launch(void* const* d_in, const int* in_sizes, int n_in,
                              void* d_out, int out_size, void* d_ws, size_t ws_size,
                              hipStream_t stream) {
    (void)in_sizes; (void)n_in; (void)out_size;
    const float* x     = (const float*)d_in[0];
    const float* w1r   = (const float*)d_in[1];
    const float* w1i   = (const float*)d_in[2];
    const float* w2r   = (const float*)d_in[3];
    const float* w2i   = (const float*)d_in[4];
    const float* mlp1w = (const float*)d_in[5];
    const float* mlp1b = (const float*)d_in[6];
    const float* mlp2w = (const float*)d_in[7];
    const float* mlp2b = (const float*)d_in[8];
    const float* wsw   = (const float*)d_in[9];
    const float* wsb   = (const float*)d_in[10];
    const float* fc0w  = (const float*)d_in[11];
    const float* fc0b  = (const float*)d_in[12];
    const float* fc1aw = (const float*)d_in[13];
    const float* fc1ab = (const float*)d_in[14];
    const float* fc1bw = (const float*)d_in[15];
    const float* fc1bb = (const float*)d_in[16];
    float* out = (float*)d_out;

    float* ws   = (float*)d_ws;
    float* xA   = ws;                        // 33,554,432
    float* T    = ws + 33554432;             //  8,388,608 (Z buffer)
    float* F    = T + 8388608;               //  2,097,152
    float* Ga   = F + 2097152;               //  2,097,152
    float* tabH = Ga + 2097152;              //  8192
    unsigned short* wpack = (unsigned short*)(tabH + 8192);  // 13*32768 ushort
    unsigned short* efp   = wpack + 13 * 32768;              // 8192 ushort
    unsigned short* ef2   = efp + 8192;                      // 8192 ushort
    unsigned short* ef3   = ef2 + 8192;                      // 32768 ushort
    float* Gb   = (float*)(ef3 + 32768);     //  2,097,152 (optional)
    size_t need_split = ((char*)(Gb + 2097152)) - (char*)d_ws;
    bool isplit = ws_size >= need_split;

    k_init_tables<<<32, 256, 0, stream>>>(tabH);
    k_pack_w<<<832, 256, 0, stream>>>(mlp1w, mlp2w, wsw, fc1aw, wpack);
    k_pack_ef<<<64, 256, 0, stream>>>(efp, ef2, ef3);
    k_lift<<<32768, 256, 0, stream>>>(x, fc0w, fc0b, xA);

    for (int l = 0; l < 4; ++l) {
        k_fwd<<<2048, 256, 0, stream>>>(xA, F, efp, ef3);
        const float* l1r = w1r + (size_t)l * 4194304;
        const float* l1i = w1i + (size_t)l * 4194304;
        const float* l2r = w2r + (size_t)l * 4194304;
        const float* l2i = w2i + (size_t)l * 4194304;
        if (isplit) {
            k_modemix<1><<<dim3(8, 32, 8), 256, 0, stream>>>(F, Ga, Gb, l1r, l1i, l2r, l2i);
            k_idft_h<1><<<2048, 256, 0, stream>>>(Ga, Gb, T, tabH);
        } else {
            k_modemix<0><<<dim3(8, 32, 4), 256, 0, stream>>>(F, Ga, Ga, l1r, l1i, l2r, l2i);
            k_idft_h<0><<<2048, 256, 0, stream>>>(Ga, Ga, T, tabH);
        }
        const unsigned short* w1p  = wpack + (size_t)l * 32768;
        const unsigned short* w2p  = wpack + (size_t)(4 + l) * 32768;
        const unsigned short* wskp = wpack + (size_t)(8 + l) * 32768;
        if (l < 3)
            k_layer<1><<<dim3(256, 16), 256, 0, stream>>>(T, xA,
                w1p, mlp1b + l * 128, w2p, mlp2b + l * 128,
                wskp, wsb + l * 128, ef2, xA);
        else
            k_layer<0><<<dim3(256, 16), 256, 0, stream>>>(T, xA,
                w1p, mlp1b + l * 128, w2p, mlp2b + l * 128,
                wskp, wsb + l * 128, ef2, xA);
    }
    k_proj<<<dim3(256, 16), 256, 0, stream>>>(xA, wpack + (size_t)12 * 32768,
        fc1ab, fc1bw, fc1bb, out);
}

// Round 8
// 1144.052 us; speedup vs baseline: 3.6975x; 1.0141x over previous
//
#include <hip/hip_runtime.h>
#include <hip/hip_bf16.h>
#include <math.h>

#define PI_F 3.14159265358979323846f

typedef __attribute__((ext_vector_type(8))) short s8v;
typedef __attribute__((ext_vector_type(4))) short s4v;
typedef __attribute__((ext_vector_type(4))) float f4v;

#define MFMA16(a, b, c) __builtin_amdgcn_mfma_f32_16x16x32_bf16(a, b, c, 0, 0, 0)

// fast erf, A&S 7.1.26, |err| <= ~1e-6 (rcp adds ~1ulp)
__device__ __forceinline__ float erf_f(float x) {
    float a = fabsf(x);
    float t = __builtin_amdgcn_rcpf(fmaf(0.3275911f, a, 1.0f));
    float p = t * fmaf(t, fmaf(t, fmaf(t, fmaf(t, 1.061405429f, -1.453152027f),
                1.421413741f), -0.284496736f), 0.254829592f);
    float r = 1.0f - p * __expf(-a * a);
    return copysignf(r, x);
}
__device__ __forceinline__ float gelu_f(float x) {
    return 0.5f * x * (1.0f + erf_f(x * 0.70710678118654752440f));
}

// split x = hi + lo, both bf16, via native HW converts (RNE). lo corrects hi
// exactly; total rel err ~2^-17.
__device__ __forceinline__ void split_bf16(float x, unsigned short& h, unsigned short& l) {
    __hip_bfloat16 hb = __float2bfloat16(x);
    float hf = __bfloat162float(hb);
    __hip_bfloat16 lb = __float2bfloat16(x - hf);
    h = __builtin_bit_cast(unsigned short, hb);
    l = __builtin_bit_cast(unsigned short, lb);
}

// pack 8 fp32 (consecutive k, k0 mult of 8) into swizzled hi/lo LDS B-buffer
// layout: [px 0..63][k 0..127] bf16, hi @0, lo @16384; byte ^= ((px&15)<<4)
__device__ __forceinline__ void pack_write8(char* Bb, int px, int k0, const float* v) {
    s8v hv, lv;
    #pragma unroll
    for (int j = 0; j < 8; ++j) {
        unsigned short h, l;
        split_bf16(v[j], h, l);
        hv[j] = (short)h; lv[j] = (short)l;
    }
    int byt = px * 256 + ((k0 * 2) ^ ((px & 15) << 4));
    *(s8v*)(Bb + byt) = hv;
    *(s8v*)(Bb + 16384 + byt) = lv;
}

// 128(o) x 64(px) x 32*KCN(k) GEMM accumulate via split-bf16 MFMA, kc in [KC0,KC0+KCN)
template<int KC0, int KCN>
__device__ __forceinline__ void gemm_range(const char* Bb, const unsigned short* wp,
                                           int lane, int wv, f4v acc[2][4]) {
    #pragma unroll
    for (int kc = KC0; kc < KC0 + KCN; ++kc) {
        s8v bh[4], bl[4];
        int k0 = kc * 32 + ((lane >> 4) << 3);
        #pragma unroll
        for (int pt = 0; pt < 4; ++pt) {
            int px = pt * 16 + (lane & 15);
            int byt = px * 256 + ((k0 * 2) ^ ((px & 15) << 4));
            bh[pt] = *(const s8v*)(Bb + byt);
            bl[pt] = *(const s8v*)(Bb + 16384 + byt);
        }
        #pragma unroll
        for (int oi = 0; oi < 2; ++oi) {
            const unsigned short* ap = wp + (wv * 2 + oi) * 2048 + kc * 512 + lane * 8;
            s8v ah = *(const s8v*)ap;
            s8v al = *(const s8v*)(ap + 16384);
            #pragma unroll
            for (int pt = 0; pt < 4; ++pt) {
                acc[oi][pt] = MFMA16(ah, bh[pt], acc[oi][pt]);
                acc[oi][pt] = MFMA16(ah, bl[pt], acc[oi][pt]);
                acc[oi][pt] = MFMA16(al, bh[pt], acc[oi][pt]);
            }
        }
    }
}

// ---------------- weight pre-split+pack: 13 fp32 128x128 mats ----------------
__global__ __launch_bounds__(256) void k_pack_w(const float* __restrict__ mlp1w,
        const float* __restrict__ mlp2w, const float* __restrict__ wsw,
        const float* __restrict__ fc1aw, unsigned short* __restrict__ wpack) {
    int idx = blockIdx.x * 256 + threadIdx.x;
    if (idx >= 212992) return;           // 13 * 16384
    int mat = idx >> 14, e = idx & 16383;
    const float* src = mat < 4  ? mlp1w + mat * 16384 + e
                     : mat < 8  ? mlp2w + (mat - 4) * 16384 + e
                     : mat < 12 ? wsw + (mat - 8) * 16384 + e
                                : fc1aw + e;
    float x = *src;
    unsigned short h, l;
    split_bf16(x, h, l);
    int o = e >> 7, i = e & 127;
    int pos = (o >> 4) * 2048 + (i >> 5) * 512 + (((i >> 3) & 3) * 16 + (o & 15)) * 8 + (i & 7);
    wpack[(size_t)mat * 32768 + pos] = h;
    wpack[(size_t)mat * 32768 + 16384 + pos] = l;
}

// ---------------- twiddle fragment tables ----------------
// efp: forward-w DFT B-frags [kc4][nt2][lane64][j8], hi @0, lo @+4096 (ushort)
// ef2: inverse-w DFT B-frags [wt8][lane64][j8], hi @0, lo @+4096, incl irfft scale
// ef3: forward-h DFT doubled-real B-frags [ct4][kt8][lane64][j8], hi @0, lo @+16384
__global__ void k_pack_ef(unsigned short* __restrict__ efp,
                          unsigned short* __restrict__ ef2,
                          unsigned short* __restrict__ ef3) {
    int t = blockIdx.x * 256 + threadIdx.x;
    if (t < 4096) {
        int j = t & 7, lane = (t >> 3) & 63, nt = (t >> 9) & 1, kc = t >> 10;
        int w = kc * 32 + ((lane >> 4) << 3) + j;
        int q = nt * 16 + (lane & 15);
        int ky = q >> 1, c = q & 1;
        int m = (ky * w) & 127;
        float th = (2.0f * PI_F / 128.0f) * (float)m;
        float v = c ? -sinf(th) : cosf(th);
        unsigned short h, l;
        split_bf16(v, h, l);
        efp[t] = h;
        efp[4096 + t] = l;
    }
    if (t < 4096) {
        int j = t & 7, lane = (t >> 3) & 63, wt = t >> 9;
        int w = wt * 16 + (lane & 15);
        int q = ((lane >> 4) << 3) + j;
        int ky = q >> 1, c = q & 1;
        float g = (ky == 0 ? 1.0f : 2.0f) * (1.0f / 16384.0f);
        int m = (ky * w) & 127;
        float th = (2.0f * PI_F / 128.0f) * (float)m;
        float v = (c ? -sinf(th) : cosf(th)) * g;
        unsigned short h, l;
        split_bf16(v, h, l);
        ef2[t] = h;
        ef2[4096 + t] = l;
    }
    if (t < 16384) {
        int j = t & 7, lane = (t >> 3) & 63, kt = (t >> 9) & 7, ct = t >> 12;
        int k = kt * 32 + ((lane >> 4) << 3) + j;
        int col = ct * 16 + (lane & 15);
        int h = k >> 1, cb = k & 1;
        int kxi = col >> 1, cp = col & 1;
        int f = kxi < 16 ? kxi : kxi - 32;
        int m = ((f * h) % 128 + 128) & 127;
        float th = (2.0f * PI_F / 128.0f) * (float)m;
        float Er = cosf(th), Ei = -sinf(th);
        float v = (cb == 0) ? (cp == 0 ? Er : Ei) : (cp == 0 ? -Ei : Er);
        unsigned short hh, ll;
        split_bf16(v, hh, ll);
        ef3[t] = hh;
        ef3[16384 + t] = ll;
    }
}

// ---------------- tabH for inverse h-DFT ----------------
__global__ void k_init_tables(float* __restrict__ tabH) {
    int idx = blockIdx.x * 256 + threadIdx.x;
    if (idx < 8192) {
        int c = idx & 1, kxi = (idx >> 1) & 31, h = idx >> 6;
        int f = kxi < 16 ? kxi : kxi - 32;
        int m = ((f * h) % 128 + 128) & 127;
        float th = (2.0f * PI_F / 128.0f) * (float)m;
        tabH[idx] = c ? -sinf(th) : cosf(th);
    }
}

// ---------------- lifting (4 px / thread, float4) ----------------
__global__ __launch_bounds__(256) void k_lift(const float* __restrict__ xin,
        const float* __restrict__ w0, const float* __restrict__ b0,
        float* __restrict__ xout) {
    int idx = blockIdx.x * 256 + threadIdx.x;     // 8,388,608 quads
    int wq = idx & 31, h = (idx >> 5) & 127, c = (idx >> 12) & 127, b = idx >> 19;
    const float4* xp = (const float4*)(xin + ((size_t)(b * 128 + h) * 128 + wq * 4) * 2);
    float4 p01 = xp[0], p23 = xp[1];
    float wa = w0[c], wbv = w0[128 + c], wg = w0[256 + c], wd = w0[384 + c];
    float base = (float)h * (1.0f / 127.0f) * wg + b0[c];
    float ws = (1.0f / 127.0f) * wd;
    float4 v;
    v.x = p01.x * wa + p01.y * wbv + (float)(wq * 4 + 0) * ws + base;
    v.y = p01.z * wa + p01.w * wbv + (float)(wq * 4 + 1) * ws + base;
    v.z = p23.x * wa + p23.y * wbv + (float)(wq * 4 + 2) * ws + base;
    v.w = p23.z * wa + p23.w * wbv + (float)(wq * 4 + 3) * ws + base;
    *(float4*)(xout + ((size_t)(b * 128 + c) * 128 + h) * 128 + wq * 4) = v;
}

// ---------------- fused forward transform: x(b,c) -> F[bi][kxi*16+ky]cplx ------
__global__ __launch_bounds__(256) void k_fwd(const float* __restrict__ x,
        float* __restrict__ F, const unsigned short* __restrict__ efp,
        const unsigned short* __restrict__ ef3) {
    __shared__ __align__(16) char Xb[32768];
    __shared__ __align__(16) char Tq[16384];
    int t = threadIdx.x;
    int bi = blockIdx.x;
    int lane = t & 63, wv = t >> 6;
    const float4* xg = (const float4*)(x + (size_t)bi * 16384);

    for (int half = 0; half < 2; ++half) {
        __syncthreads();
        #pragma unroll
        for (int k = 0; k < 8; ++k) {
            int idx4 = k * 256 + t;
            float4 f = xg[half * 2048 + idx4];
            int row = idx4 >> 5;
            int w0 = (idx4 & 31) * 4;
            s4v h4, l4;
            const float* fp = (const float*)&f;
            #pragma unroll
            for (int q = 0; q < 4; ++q) {
                unsigned short hh, ll;
                split_bf16(fp[q], hh, ll);
                h4[q] = (short)hh; l4[q] = (short)ll;
            }
            int byt = row * 256 + ((w0 * 2) ^ ((row & 15) << 4));
            *(s4v*)(Xb + byt) = h4;
            *(s4v*)(Xb + 16384 + byt) = l4;
        }
        __syncthreads();
        f4v acc[2];
        acc[0] = (f4v){0.f, 0.f, 0.f, 0.f};
        acc[1] = (f4v){0.f, 0.f, 0.f, 0.f};
        #pragma unroll
        for (int kc = 0; kc < 4; ++kc) {
            int row = wv * 16 + (lane & 15);
            int k0 = kc * 32 + ((lane >> 4) << 3);
            int byt = row * 256 + ((k0 * 2) ^ ((row & 15) << 4));
            s8v ah = *(const s8v*)(Xb + byt);
            s8v al = *(const s8v*)(Xb + 16384 + byt);
            #pragma unroll
            for (int nt = 0; nt < 2; ++nt) {
                const unsigned short* bp = efp + ((kc * 2 + nt) * 64 + lane) * 8;
                s8v bh = *(const s8v*)bp;
                s8v bl = *(const s8v*)(bp + 4096);
                acc[nt] = MFMA16(ah, bh, acc[nt]);
                acc[nt] = MFMA16(ah, bl, acc[nt]);
                acc[nt] = MFMA16(al, bh, acc[nt]);
            }
        }
        // scatter T (split-bf16) into Tq: T[h][q] -> Tq[ky=q>>1][k=2h+(q&1)]
        #pragma unroll
        for (int nt = 0; nt < 2; ++nt) {
            int q = nt * 16 + (lane & 15);
            int ky = q >> 1, c = q & 1;
            #pragma unroll
            for (int r = 0; r < 4; ++r) {
                int h = half * 64 + wv * 16 + ((lane >> 4) << 2) + r;
                unsigned short hh, ll;
                split_bf16(acc[nt][r], hh, ll);
                int byt = ky * 512 + ((4 * h + 2 * c) ^ ((ky & 15) << 4));
                *(unsigned short*)(Tq + byt) = hh;
                *(unsigned short*)(Tq + 8192 + byt) = ll;
            }
        }
    }
    __syncthreads();
    f4v fa = (f4v){0.f, 0.f, 0.f, 0.f};
    #pragma unroll
    for (int kt = 0; kt < 8; ++kt) {
        int ky = lane & 15;
        int byt = ky * 512 + ((kt * 64 + ((lane >> 4) << 4)) ^ ((ky & 15) << 4));
        s8v ah = *(const s8v*)(Tq + byt);
        s8v al = *(const s8v*)(Tq + 8192 + byt);
        const unsigned short* bp = ef3 + ((wv * 8 + kt) * 64 + lane) * 8;
        s8v bh = *(const s8v*)bp;
        s8v bl = *(const s8v*)(bp + 16384);
        fa = MFMA16(ah, bh, fa);
        fa = MFMA16(ah, bl, fa);
        fa = MFMA16(al, bh, fa);
    }
    int col = wv * 16 + (lane & 15);
    int kxi = col >> 1, cp = col & 1;
    float* Fb = F + (size_t)bi * 1024 + kxi * 32 + cp;
    #pragma unroll
    for (int r = 0; r < 4; ++r) {
        int ky = ((lane >> 4) << 2) + r;
        Fb[ky * 2] = fa[r];
    }
}

// ---------------- per-mode complex C x C mix ----------------
// ISPLIT=1: z = bh*2+ih (4 blocks): 8 batches/thread, i-half -> Ga/Gb partials.
// ISPLIT=0: z = b-quarter (4 blocks): 4 batches/thread, full i, Ga only.
template<int ISPLIT>
__global__ __launch_bounds__(256) void k_modemix(const float* __restrict__ F,
        float* __restrict__ Ga, float* __restrict__ Gb,
        const float* __restrict__ w1r, const float* __restrict__ w1i,
        const float* __restrict__ w2r, const float* __restrict__ w2i) {
    int t = threadIdx.x;
    int m = blockIdx.x * 64 + (t & 63);
    int o = blockIdx.y * 4 + (t >> 6);
    int bz = blockIdx.z;
    constexpr int NB = ISPLIT ? 8 : 4;
    int ih = ISPLIT ? (bz & 1) : 0;
    int b0 = ISPLIT ? ((bz >> 1) * 8) : (bz * 4);
    const float* wrp = (m < 256) ? w1r : w2r;
    const float* wip = (m < 256) ? w1i : w2i;
    int ms = m & 255;
    float accr[NB], acci[NB];
    #pragma unroll
    for (int b = 0; b < NB; ++b) { accr[b] = 0.f; acci[b] = 0.f; }
    const int ni = ISPLIT ? 64 : 128;
    const size_t i0 = (size_t)ih * 64;
    const float* wrb = wrp + (i0 * 128 + o) * 256 + ms;
    const float* wib = wip + (i0 * 128 + o) * 256 + ms;
    const float2* F2 = (const float2*)F + (size_t)b0 * 65536 + i0 * 512 + m;
    #pragma unroll 4
    for (int ii = 0; ii < ni; ++ii) {
        float wr = wrb[(size_t)ii * 32768];
        float wi = wib[(size_t)ii * 32768];
        const float2* Fp = F2 + (size_t)ii * 512;
        #pragma unroll
        for (int b = 0; b < NB; ++b) {
            float2 f = Fp[(size_t)b * 65536];
            accr[b] += f.x * wr - f.y * wi;
            acci[b] += f.x * wi + f.y * wr;
        }
    }
    float2* Gp = (float2*)((ISPLIT && ih) ? Gb : Ga);
    #pragma unroll
    for (int b = 0; b < NB; ++b) {
        Gp[(size_t)(b0 + b) * 65536 + (size_t)o * 512 + m] = make_float2(accr[b], acci[b]);
    }
}

// ---------------- inverse DFT along h (optionally summing two partial G) ------
template<int ADD>
__global__ __launch_bounds__(256) void k_idft_h(const float* __restrict__ G,
        const float* __restrict__ G2, float* __restrict__ Z,
        const float* __restrict__ tabH) {
    __shared__ float Gs[1024];
    __shared__ float Eh[8192];
    int t = threadIdx.x, bo = blockIdx.x;
    #pragma unroll
    for (int k = 0; k < 32; ++k) Eh[k * 256 + t] = tabH[k * 256 + t];
    const float* Gp = G + (size_t)bo * 1024;
    const float* G2p = G2 + (size_t)bo * 1024;
    #pragma unroll
    for (int k = 0; k < 4; ++k)
        Gs[k * 256 + t] = ADD ? (Gp[k * 256 + t] + G2p[k * 256 + t]) : Gp[k * 256 + t];
    __syncthreads();
    int ky = t & 15, hb = t >> 4;
    float zr[8], zi[8];
    #pragma unroll
    for (int j = 0; j < 8; ++j) { zr[j] = 0.f; zi[j] = 0.f; }
    for (int kxi = 0; kxi < 32; ++kxi) {
        float gr = Gs[(kxi * 16 + ky) * 2], gi = Gs[(kxi * 16 + ky) * 2 + 1];
        #pragma unroll
        for (int j = 0; j < 8; ++j) {
            int h = hb + 16 * j;
            float c = Eh[h * 64 + kxi * 2], s = Eh[h * 64 + kxi * 2 + 1];
            zr[j] += gr * c + gi * s;
            zi[j] += gi * c - gr * s;
        }
    }
    float* Zp = Z + (size_t)bo * 4096;
    #pragma unroll
    for (int j = 0; j < 8; ++j) {
        int h = hb + 16 * j;
        Zp[h * 32 + ky * 2] = zr[j];
        Zp[h * 32 + ky * 2 + 1] = zi[j];
    }
}

// ---------------- fused layer tail: Z -> S (MFMA idft_w) -> MLP + skip, in-place ----
template<int ACT>
__global__ __launch_bounds__(256, 3) void k_layer(
    const float* __restrict__ Zbuf, const float* __restrict__ xin,
    const unsigned short* __restrict__ w1p, const float* __restrict__ b1,
    const unsigned short* __restrict__ w2p, const float* __restrict__ b2,
    const unsigned short* __restrict__ wskp, const float* __restrict__ bsk,
    const unsigned short* __restrict__ ef2, float* __restrict__ xout)
{
    __shared__ __align__(16) char Bb[32768];
    int t = threadIdx.x;
    int b = blockIdx.y;
    int p0 = blockIdx.x * 64;
    int h = p0 >> 7, w0 = p0 & 127;
    int lane = t & 63, wv = t >> 6;

    // ---- P0: S = Z . E2 via MFMA (K=32), pack C-frags into Bb ----
    {
        int q0 = (lane >> 4) << 3;
        s8v zah[2], zal[2];
        #pragma unroll
        for (int ct = 0; ct < 2; ++ct) {
            int c = wv * 32 + ct * 16 + (lane & 15);
            const float* zp = Zbuf + ((size_t)(b * 128 + c) * 128 + h) * 32 + q0;
            float4 z0 = *(const float4*)zp;
            float4 z1 = *(const float4*)(zp + 4);
            float zv[8] = {z0.x, z0.y, z0.z, z0.w, z1.x, z1.y, z1.z, z1.w};
            #pragma unroll
            for (int j = 0; j < 8; ++j) {
                unsigned short hh, ll;
                split_bf16(zv[j], hh, ll);
                zah[ct][j] = (short)hh; zal[ct][j] = (short)ll;
            }
        }
        int wtg0 = w0 >> 4;
        #pragma unroll
        for (int wt = 0; wt < 4; ++wt) {
            const unsigned short* bp = ef2 + ((wtg0 + wt) * 64 + lane) * 8;
            s8v bh = *(const s8v*)bp;
            s8v bl = *(const s8v*)(bp + 4096);
            #pragma unroll
            for (int ct = 0; ct < 2; ++ct) {
                f4v c4 = (f4v){0.f, 0.f, 0.f, 0.f};
                c4 = MFMA16(zah[ct], bh, c4);
                c4 = MFMA16(zah[ct], bl, c4);
                c4 = MFMA16(zal[ct], bh, c4);
                int px = wt * 16 + (lane & 15);
                int c0 = wv * 32 + ct * 16 + ((lane >> 4) << 2);
                s4v h4, l4;
                #pragma unroll
                for (int r = 0; r < 4; ++r) {
                    unsigned short hh, ll;
                    split_bf16(c4[r], hh, ll);
                    h4[r] = (short)hh; l4[r] = (short)ll;
                }
                int byt = px * 256 + ((c0 * 2) ^ ((px & 15) << 4));
                *(s4v*)(Bb + byt) = h4;
                *(s4v*)(Bb + 16384 + byt) = l4;
            }
        }
    }
    __syncthreads();

    f4v acc[2][4];
    #pragma unroll
    for (int oi = 0; oi < 2; ++oi)
        #pragma unroll
        for (int pt = 0; pt < 4; ++pt) acc[oi][pt] = (f4v){0.f, 0.f, 0.f, 0.f};

    // ---- P1: acc = W1 . S ----
    gemm_range<0, 4>(Bb, w1p, lane, wv, acc);
    __syncthreads();                       // all S reads done

    // issue x prefetch half 0 (channels 0..63); lands during Mid-pack + P2
    float xr[16];
    #pragma unroll
    for (int j = 0; j < 16; ++j)
        xr[j] = xin[((size_t)(b * 128 + wv * 16 + j)) * 16384 + p0 + lane];

    // Mid = gelu(acc + b1) -> overwrite Bb
    #pragma unroll
    for (int oi = 0; oi < 2; ++oi) {
        int o0 = wv * 32 + oi * 16 + ((lane >> 4) << 2);
        float bv[4];
        #pragma unroll
        for (int r = 0; r < 4; ++r) bv[r] = b1[o0 + r];
        #pragma unroll
        for (int pt = 0; pt < 4; ++pt) {
            int px = pt * 16 + (lane & 15);
            s4v h4, l4;
            #pragma unroll
            for (int r = 0; r < 4; ++r) {
                unsigned short hh, ll;
                split_bf16(gelu_f(acc[oi][pt][r] + bv[r]), hh, ll);
                h4[r] = (short)hh; l4[r] = (short)ll;
            }
            int byt = px * 256 + ((o0 * 2) ^ ((px & 15) << 4));
            *(s4v*)(Bb + byt) = h4;
            *(s4v*)(Bb + 16384 + byt) = l4;
            acc[oi][pt] = (f4v){0.f, 0.f, 0.f, 0.f};
        }
    }
    __syncthreads();

    // ---- P2: acc = W2 . Mid ----
    gemm_range<0, 4>(Bb, w2p, lane, wv, acc);
    __syncthreads();                       // all Mid reads done

    // ---- P3: skip GEMM in two K-halves, packing one half while computing the other ----
    pack_write8(Bb, lane, wv * 16, xr);
    pack_write8(Bb, lane, wv * 16 + 8, xr + 8);
    #pragma unroll
    for (int j = 0; j < 16; ++j)           // half 1 (channels 64..127)
        xr[j] = xin[((size_t)(b * 128 + 64 + wv * 16 + j)) * 16384 + p0 + lane];
    __syncthreads();
    gemm_range<0, 2>(Bb, wskp, lane, wv, acc);
    pack_write8(Bb, lane, 64 + wv * 16, xr);
    pack_write8(Bb, lane, 64 + wv * 16 + 8, xr + 8);
    __syncthreads();
    gemm_range<2, 2>(Bb, wskp, lane, wv, acc);

    // ---- epilogue: in-place write ----
    #pragma unroll
    for (int oi = 0; oi < 2; ++oi) {
        int o0 = wv * 32 + oi * 16 + ((lane >> 4) << 2);
        float bv[4];
        #pragma unroll
        for (int r = 0; r < 4; ++r) bv[r] = b2[o0 + r] + bsk[o0 + r];
        #pragma unroll
        for (int pt = 0; pt < 4; ++pt) {
            int px = pt * 16 + (lane & 15);
            #pragma unroll
            for (int r = 0; r < 4; ++r) {
                float xv = acc[oi][pt][r] + bv[r];
                if (ACT) xv = gelu_f(xv);
                xout[((size_t)(b * 128 + o0 + r)) * 16384 + p0 + px] = xv;
            }
        }
    }
}

// ---------------- fused projection ----------------
__global__ __launch_bounds__(256) void k_proj(const float* __restrict__ xin,
        const unsigned short* __restrict__ wap, const float* __restrict__ ba,
        const float* __restrict__ wb, const float* __restrict__ bb,
        float* __restrict__ outp) {
    __shared__ __align__(16) char Bb[32768];
    __shared__ float Red[256];
    int t = threadIdx.x;
    int b = blockIdx.y;
    int p0 = blockIdx.x * 64;
    int lane = t & 63, wv = t >> 6;

    float xr[16];
    #pragma unroll
    for (int j = 0; j < 16; ++j)
        xr[j] = xin[((size_t)(b * 128 + wv * 16 + j)) * 16384 + p0 + lane];
    pack_write8(Bb, lane, wv * 16, xr);
    pack_write8(Bb, lane, wv * 16 + 8, xr + 8);
    #pragma unroll
    for (int j = 0; j < 16; ++j)
        xr[j] = xin[((size_t)(b * 128 + 64 + wv * 16 + j)) * 16384 + p0 + lane];
    pack_write8(Bb, lane, 64 + wv * 16, xr);
    pack_write8(Bb, lane, 64 + wv * 16 + 8, xr + 8);
    __syncthreads();

    f4v acc[2][4];
    #pragma unroll
    for (int oi = 0; oi < 2; ++oi)
        #pragma unroll
        for (int pt = 0; pt < 4; ++pt) acc[oi][pt] = (f4v){0.f, 0.f, 0.f, 0.f};
    gemm_range<0, 4>(Bb, wap, lane, wv, acc);

    float pxsum[4] = {0.f, 0.f, 0.f, 0.f};
    #pragma unroll
    for (int oi = 0; oi < 2; ++oi) {
        int o0 = wv * 32 + oi * 16 + ((lane >> 4) << 2);
        #pragma unroll
        for (int r = 0; r < 4; ++r) {
            float bav = ba[o0 + r];
            float wbv = wb[o0 + r];
            #pragma unroll
            for (int pt = 0; pt < 4; ++pt)
                pxsum[pt] += wbv * gelu_f(acc[oi][pt][r] + bav);
        }
    }
    #pragma unroll
    for (int pt = 0; pt < 4; ++pt) {
        float v = pxsum[pt];
        v += __shfl_xor(v, 16);
        v += __shfl_xor(v, 32);
        if (lane < 16) Red[wv * 64 + pt * 16 + lane] = v;
    }
    __syncthreads();
    if (t < 64)
        outp[(size_t)b * 16384 + p0 + t] = bb[0] + Red[t] + Red[64 + t] + Red[128 + t] + Red[192 + t];
}

extern "C" void kernel_launch(void* const* d_in, const int* in_sizes, int n_in,
                              void* d_out, int out_size, void* d_ws, size_t ws_size,
                              hipStream_t stream) {
    (void)in_sizes; (void)n_in; (void)out_size;
    const float* x     = (const float*)d_in[0];
    const float* w1r   = (const float*)d_in[1];
    const float* w1i   = (const float*)d_in[2];
    const float* w2r   = (const float*)d_in[3];
    const float* w2i   = (const float*)d_in[4];
    const float* mlp1w = (const float*)d_in[5];
    const float* mlp1b = (const float*)d_in[6];
    const float* mlp2w = (const float*)d_in[7];
    const float* mlp2b = (const float*)d_in[8];
    const float* wsw   = (const float*)d_in[9];
    const float* wsb   = (const float*)d_in[10];
    const float* fc0w  = (const float*)d_in[11];
    const float* fc0b  = (const float*)d_in[12];
    const float* fc1aw = (const float*)d_in[13];
    const float* fc1ab = (const float*)d_in[14];
    const float* fc1bw = (const float*)d_in[15];
    const float* fc1bb = (const float*)d_in[16];
    float* out = (float*)d_out;

    float* ws   = (float*)d_ws;
    float* xA   = ws;                        // 33,554,432
    float* T    = ws + 33554432;             //  8,388,608 (Z buffer)
    float* F    = T + 8388608;               //  2,097,152
    float* Ga   = F + 2097152;               //  2,097,152
    float* tabH = Ga + 2097152;              //  8192
    unsigned short* wpack = (unsigned short*)(tabH + 8192);  // 13*32768 ushort
    unsigned short* efp   = wpack + 13 * 32768;              // 8192 ushort
    unsigned short* ef2   = efp + 8192;                      // 8192 ushort
    unsigned short* ef3   = ef2 + 8192;                      // 32768 ushort
    float* Gb   = (float*)(ef3 + 32768);     //  2,097,152 (optional)
    size_t need_split = ((char*)(Gb + 2097152)) - (char*)d_ws;
    bool isplit = ws_size >= need_split;

    k_init_tables<<<32, 256, 0, stream>>>(tabH);
    k_pack_w<<<832, 256, 0, stream>>>(mlp1w, mlp2w, wsw, fc1aw, wpack);
    k_pack_ef<<<64, 256, 0, stream>>>(efp, ef2, ef3);
    k_lift<<<32768, 256, 0, stream>>>(x, fc0w, fc0b, xA);

    for (int l = 0; l < 4; ++l) {
        k_fwd<<<2048, 256, 0, stream>>>(xA, F, efp, ef3);
        const float* l1r = w1r + (size_t)l * 4194304;
        const float* l1i = w1i + (size_t)l * 4194304;
        const float* l2r = w2r + (size_t)l * 4194304;
        const float* l2i = w2i + (size_t)l * 4194304;
        if (isplit) {
            k_modemix<1><<<dim3(8, 32, 4), 256, 0, stream>>>(F, Ga, Gb, l1r, l1i, l2r, l2i);
            k_idft_h<1><<<2048, 256, 0, stream>>>(Ga, Gb, T, tabH);
        } else {
            k_modemix<0><<<dim3(8, 32, 4), 256, 0, stream>>>(F, Ga, Ga, l1r, l1i, l2r, l2i);
            k_idft_h<0><<<2048, 256, 0, stream>>>(Ga, Ga, T, tabH);
        }
        const unsigned short* w1p  = wpack + (size_t)l * 32768;
        const unsigned short* w2p  = wpack + (size_t)(4 + l) * 32768;
        const unsigned short* wskp = wpack + (size_t)(8 + l) * 32768;
        if (l < 3)
            k_layer<1><<<dim3(256, 16), 256, 0, stream>>>(T, xA,
                w1p, mlp1b + l * 128, w2p, mlp2b + l * 128,
                wskp, wsb + l * 128, ef2, xA);
        else
            k_layer<0><<<dim3(256, 16), 256, 0, stream>>>(T, xA,
                w1p, mlp1b + l * 128, w2p, mlp2b + l * 128,
                wskp, wsb + l * 128, ef2, xA);
    }
    k_proj<<<dim3(256, 16), 256, 0, stream>>>(xA, wpack + (size_t)12 * 32768,
        fc1ab, fc1bw, fc1bb, out);
}